// Round 2
// 1265.083 us; speedup vs baseline: 1.6154x; 1.6154x over previous
//
#include <hip/hip_runtime.h>
#include <math.h>

typedef unsigned short bfu;
typedef __attribute__((ext_vector_type(4))) float  f32x4;
typedef __attribute__((ext_vector_type(8))) short  bf16x8;

// ---------- dtype-dual scalar load/store ----------
__device__ __forceinline__ float b2f(bfu v) { return __uint_as_float((unsigned)v << 16); }
__device__ __forceinline__ bfu f2b(float f) {
    unsigned u = __float_as_uint(f);
    u += 0x7fffu + ((u >> 16) & 1u);   // RNE
    return (bfu)(u >> 16);
}
// split fp32 into hi+lo bf16 (hi = RNE(x), lo = RNE(x - hi)); captures ~16 mantissa bits
__device__ __forceinline__ void splitf(float x, bfu& h, bfu& l) {
    h = f2b(x);
    l = f2b(x - b2f(h));
}
template<bool F32> __device__ __forceinline__ float ldg(const void* p, size_t i) {
    if (F32) return ((const float*)p)[i];
    else     return b2f(((const bfu*)p)[i]);
}
template<bool F32> __device__ __forceinline__ void stg(void* p, size_t i, float v) {
    if (F32) ((float*)p)[i] = v;
    else     ((bfu*)p)[i] = f2b(v);
}

// Problem constants
#define CC    192
#define C3    576
#define CM    768
#define MROWS 131072   // 8*128*128
#define SHIFT 4
#define WBYTES 1769472 // split+transposed weight area in workspace

// ---------------- dtype probe ----------------
__global__ void detect_kernel(const void* x, int* flag) {
    __shared__ int bad;
    if (threadIdx.x == 0) bad = 0;
    __syncthreads();
    int local = 0;
    for (int i = 0; i < 16; i++) {
        float v = b2f(((const bfu*)x)[threadIdx.x + i * 256]);
        if (!(fabsf(v) < 1000.0f)) local = 1;
    }
    if (local) atomicOr(&bad, 1);
    __syncthreads();
    if (threadIdx.x == 0) *flag = bad;          // 1 -> fp32, 0 -> bf16
}

// ---------------- weight prep: split + transpose ----------------
// dst[n][k] = split(W[k][n]); tiny one-time kernel, matrices are L2-resident.
__global__ __launch_bounds__(64) void prep_kernel(
    const int* __restrict__ flag, const void* __restrict__ w,
    bfu* __restrict__ dh, bfu* __restrict__ dl, int K, int N)
{
    const int k = blockIdx.x * 64 + threadIdx.x;
    const int n = blockIdx.y;
    float v = (*flag) ? ((const float*)w)[(size_t)k * N + n]
                      : b2f(((const bfu*)w)[(size_t)k * N + n]);
    bfu h, l;
    splitf(v, h, l);
    dh[(size_t)n * K + k] = h;
    dl[(size_t)n * K + k] = l;
}

// ---------------- LayerNorm -> split bf16 pair ----------------
template<bool REMAP, bool F32>
__device__ void ln_body(const void* x, const void* sc, const void* bi,
                        bfu* oh, bfu* ol, int row0)
{
    const int rg = row0 + blockIdx.x;
    size_t src;
    if (REMAP) {
        int w = rg >> 6, n = rg & 63;
        int b = w >> 8, wi = (w >> 4) & 15, wj = w & 15;
        int ii = wi * 8 + (n >> 3), jj = wj * 8 + (n & 7);
        int si = (ii + SHIFT) & 127, sj = (jj + SHIFT) & 127;
        src = (((size_t)b << 14) + ((size_t)si << 7) + sj) * CC;
    } else {
        src = (size_t)rg * CC;
    }
    const int t = threadIdx.x;
    float v0 = ldg<F32>(x, src + t);
    float v1 = ldg<F32>(x, src + t + 64);
    float v2 = ldg<F32>(x, src + t + 128);
    float sum = v0 + v1 + v2;
    float sq  = v0 * v0 + v1 * v1 + v2 * v2;
    #pragma unroll
    for (int off = 32; off > 0; off >>= 1) {
        sum += __shfl_xor(sum, off);
        sq  += __shfl_xor(sq, off);
    }
    float mu  = sum * (1.0f / 192.0f);
    float var = sq * (1.0f / 192.0f) - mu * mu;
    float rs  = rsqrtf(var + 1e-5f);
    size_t dst = (size_t)blockIdx.x * CC;
    float r0 = (v0 - mu) * rs * ldg<F32>(sc, t)       + ldg<F32>(bi, t);
    float r1 = (v1 - mu) * rs * ldg<F32>(sc, t + 64)  + ldg<F32>(bi, t + 64);
    float r2 = (v2 - mu) * rs * ldg<F32>(sc, t + 128) + ldg<F32>(bi, t + 128);
    bfu h, l;
    splitf(r0, h, l); oh[dst + t]       = h; ol[dst + t]       = l;
    splitf(r1, h, l); oh[dst + t + 64]  = h; ol[dst + t + 64]  = l;
    splitf(r2, h, l); oh[dst + t + 128] = h; ol[dst + t + 128] = l;
}

template<bool REMAP>
__global__ __launch_bounds__(64) void ln_kernel(
    const int* __restrict__ flag, const void* __restrict__ x,
    const void* __restrict__ sc, const void* __restrict__ bi,
    bfu* __restrict__ oh, bfu* __restrict__ ol, int row0)
{
    if (*flag) ln_body<REMAP, true>(x, sc, bi, oh, ol, row0);
    else       ln_body<REMAP, false>(x, sc, bi, oh, ol, row0);
}

// ---------------- MFMA GEMM (split-bf16 fp32 emulation) ----------------
// A: pre-split (Ah,Al) bf16 [M][K] row-major, chunk-local rows.
// B: pre-split+transposed (BhT,BlT) bf16 [N][K].
// acc = Ah*Bh + Al*Bh (+ Ah*Bl if F32; in bf16 mode weight lo == 0).
// MODE 0: -> fp32 out (qkv), chunk-local
// MODE 1: + inverse shift/window row map + residual(x dual) -> d_out dual
// MODE 2: + exact GELU -> split bf16 pair (mlp hidden), chunk-local
// MODE 3: + residual(d_out dual, global rows) -> d_out dual
template<int MODE, bool F32>
__device__ void gemm_body(const bfu* __restrict__ Ah, const bfu* __restrict__ Al,
                          const bfu* __restrict__ Bh, const bfu* __restrict__ Bl,
                          const void* __restrict__ bias, const void* __restrict__ res,
                          void* __restrict__ out, bfu* __restrict__ outL,
                          int K, int Ncols, int row0)
{
    __shared__ __align__(16) bfu AsH[128][40];
    __shared__ __align__(16) bfu AsL[128][40];
    __shared__ __align__(16) bfu BsH[64][40];
    __shared__ __align__(16) bfu BsL[64][40];
    const int t  = threadIdx.x;
    const int m0 = blockIdx.y * 128;
    const int n0 = blockIdx.x * 64;
    const int am = t >> 1, ak = (t & 1) * 16;     // A stage: 16 elems along K
    const int bn = t >> 2, bk = (t & 3) * 8;      // B stage: 8 elems along K
    const int l  = t & 63, wv = t >> 6;
    const int wm = wv >> 1, wn = wv & 1;          // 2x2 wave grid
    const int fr = l & 15, fk = (l >> 4) * 8;     // fragment row/col, k offset

    const bfu* gAh = Ah + (size_t)(m0 + am) * K + ak;
    const bfu* gAl = Al + (size_t)(m0 + am) * K + ak;
    const bfu* gBh = Bh + (size_t)(n0 + bn) * K + bk;
    const bfu* gBl = Bl + (size_t)(n0 + bn) * K + bk;

    f32x4 acc[4][2];
    #pragma unroll
    for (int mt = 0; mt < 4; mt++)
        #pragma unroll
        for (int nt = 0; nt < 2; nt++)
            acc[mt][nt] = f32x4{0.f, 0.f, 0.f, 0.f};

    for (int k0 = 0; k0 < K; k0 += 32) {
        f32x4 ra0 = *(const f32x4*)(gAh + k0);
        f32x4 ra1 = *(const f32x4*)(gAh + k0 + 8);
        f32x4 rl0 = *(const f32x4*)(gAl + k0);
        f32x4 rl1 = *(const f32x4*)(gAl + k0 + 8);
        f32x4 rbh = *(const f32x4*)(gBh + k0);
        f32x4 rbl = f32x4{0.f, 0.f, 0.f, 0.f};
        if (F32) rbl = *(const f32x4*)(gBl + k0);
        __syncthreads();
        *(f32x4*)&AsH[am][ak]     = ra0;
        *(f32x4*)&AsH[am][ak + 8] = ra1;
        *(f32x4*)&AsL[am][ak]     = rl0;
        *(f32x4*)&AsL[am][ak + 8] = rl1;
        *(f32x4*)&BsH[bn][bk] = rbh;
        if (F32) *(f32x4*)&BsL[bn][bk] = rbl;
        __syncthreads();

        bf16x8 ah[4], al[4], bh[2], bl[2];
        #pragma unroll
        for (int nt = 0; nt < 2; nt++) {
            bh[nt] = *(const bf16x8*)&BsH[wn * 32 + nt * 16 + fr][fk];
            if (F32) bl[nt] = *(const bf16x8*)&BsL[wn * 32 + nt * 16 + fr][fk];
        }
        #pragma unroll
        for (int mt = 0; mt < 4; mt++) {
            ah[mt] = *(const bf16x8*)&AsH[wm * 64 + mt * 16 + fr][fk];
            al[mt] = *(const bf16x8*)&AsL[wm * 64 + mt * 16 + fr][fk];
        }
        #pragma unroll
        for (int mt = 0; mt < 4; mt++)
            #pragma unroll
            for (int nt = 0; nt < 2; nt++) {
                acc[mt][nt] = __builtin_amdgcn_mfma_f32_16x16x32_bf16(ah[mt], bh[nt], acc[mt][nt], 0, 0, 0);
                acc[mt][nt] = __builtin_amdgcn_mfma_f32_16x16x32_bf16(al[mt], bh[nt], acc[mt][nt], 0, 0, 0);
                if (F32)
                    acc[mt][nt] = __builtin_amdgcn_mfma_f32_16x16x32_bf16(ah[mt], bl[nt], acc[mt][nt], 0, 0, 0);
            }
    }

    float bia[2];
    #pragma unroll
    for (int nt = 0; nt < 2; nt++)
        bia[nt] = ldg<F32>(bias, n0 + wn * 32 + nt * 16 + fr);

    #pragma unroll
    for (int mt = 0; mt < 4; mt++) {
        #pragma unroll
        for (int r = 0; r < 4; r++) {
            const int rl = m0 + wm * 64 + mt * 16 + (l >> 4) * 4 + r;
            size_t orow;
            if (MODE == 1) {
                int rg = row0 + rl;
                int w = rg >> 6, n = rg & 63;
                int b_ = w >> 8, wi = (w >> 4) & 15, wj = w & 15;
                int ii = wi * 8 + (n >> 3), jj = wj * 8 + (n & 7);
                int fi = (ii + SHIFT) & 127, fj = (jj + SHIFT) & 127;
                orow = ((size_t)b_ << 14) + ((size_t)fi << 7) + fj;
            } else if (MODE == 3) {
                orow = (size_t)(row0 + rl);
            } else {
                orow = (size_t)rl;
            }
            #pragma unroll
            for (int nt = 0; nt < 2; nt++) {
                size_t o = orow * Ncols + n0 + wn * 32 + nt * 16 + fr;
                float v = acc[mt][nt][r] + bia[nt];
                if (MODE == 1 || MODE == 3) v += ldg<F32>(res, o);
                if (MODE == 2) v = v * 0.5f * (1.0f + erff(v * 0.70710678118654752f));
                if (MODE == 0) {
                    ((float*)out)[o] = v;
                } else if (MODE == 2) {
                    bfu h, lo_;
                    splitf(v, h, lo_);
                    ((bfu*)out)[o] = h;
                    outL[o] = lo_;
                } else {
                    stg<F32>(out, o, v);
                }
            }
        }
    }
}

template<int MODE>
__global__ __launch_bounds__(256) void gemm_kernel(
    const int* __restrict__ flag,
    const bfu* __restrict__ Ah, const bfu* __restrict__ Al,
    const bfu* __restrict__ Bh, const bfu* __restrict__ Bl,
    const void* __restrict__ bias, const void* __restrict__ res,
    void* __restrict__ out, bfu* __restrict__ outL,
    int K, int Ncols, int row0)
{
    if (*flag) gemm_body<MODE, true >(Ah, Al, Bh, Bl, bias, res, out, outL, K, Ncols, row0);
    else       gemm_body<MODE, false>(Ah, Al, Bh, Bl, bias, res, out, outL, K, Ncols, row0);
}

// ---------------- Windowed attention (fp32 in, split bf16 out) ----------------
template<bool F32>
__device__ void attn_body(const float* qkv, const void* rpb, bfu* outH, bfu* outL)
{
    __shared__ __align__(16) float qT[32][64];
    __shared__ __align__(16) float kT[32][64];
    __shared__ __align__(16) float vsm[64][32];
    __shared__ __align__(16) float S[64][68];
    __shared__ float bias_s[225 * 6];
    const int t = threadIdx.x;
    const int w = blockIdx.x / 6;
    const int h = blockIdx.x % 6;

    for (int i = t; i < 1350; i += 256) bias_s[i] = ldg<F32>(rpb, i);
    {
        const int n = t >> 2, d0 = (t & 3) * 8;
        size_t base = (size_t)(w * 64 + n) * C3 + h * 32 + d0;
        #pragma unroll
        for (int i = 0; i < 8; i++) {
            qT[d0 + i][n]  = qkv[base + i];
            kT[d0 + i][n]  = qkv[base + 192 + i];
            vsm[n][d0 + i] = qkv[base + 384 + i];
        }
    }
    __syncthreads();

    {
        const int i0 = (t >> 4) * 4, j0 = (t & 15) * 4;
        float sacc[4][4] = {};
        #pragma unroll
        for (int kk = 0; kk < 32; kk++) {
            float4 q4 = *reinterpret_cast<float4*>(&qT[kk][i0]);
            float4 k4 = *reinterpret_cast<float4*>(&kT[kk][j0]);
            float qa[4] = {q4.x, q4.y, q4.z, q4.w};
            float kb[4] = {k4.x, k4.y, k4.z, k4.w};
            #pragma unroll
            for (int a = 0; a < 4; a++)
                #pragma unroll
                for (int b = 0; b < 4; b++)
                    sacc[a][b] += qa[a] * kb[b];
        }
        #pragma unroll
        for (int a = 0; a < 4; a++) {
            int i = i0 + a;
            #pragma unroll
            for (int b = 0; b < 4; b++) {
                int j = j0 + b;
                int rel = ((i >> 3) - (j >> 3) + 7) * 15 + ((i & 7) - (j & 7) + 7);
                S[i][j] = sacc[a][b] * 0.17677669529663687f + bias_s[rel * 6 + h];
            }
        }
    }
    __syncthreads();

    {
        const int r = t >> 2, q = (t & 3) * 16;
        float mx = -1e30f;
        #pragma unroll
        for (int j = 0; j < 16; j++) mx = fmaxf(mx, S[r][q + j]);
        mx = fmaxf(mx, __shfl_xor(mx, 1));
        mx = fmaxf(mx, __shfl_xor(mx, 2));
        float sm = 0.f;
        #pragma unroll
        for (int j = 0; j < 16; j++) { float e = __expf(S[r][q + j] - mx); S[r][q + j] = e; sm += e; }
        sm += __shfl_xor(sm, 1);
        sm += __shfl_xor(sm, 2);
        float inv = 1.0f / sm;
        #pragma unroll
        for (int j = 0; j < 16; j++) S[r][q + j] *= inv;
    }
    __syncthreads();

    {
        const int oi = (t >> 4) * 4, d0 = (t & 15) * 2;
        float a0 = 0, a1 = 0, a2 = 0, a3 = 0, c0 = 0, c1 = 0, c2 = 0, c3 = 0;
        for (int j = 0; j < 64; j++) {
            float2 vj = *reinterpret_cast<float2*>(&vsm[j][d0]);
            float s0 = S[oi][j], s1 = S[oi + 1][j], s2 = S[oi + 2][j], s3 = S[oi + 3][j];
            a0 += s0 * vj.x; c0 += s0 * vj.y;
            a1 += s1 * vj.x; c1 += s1 * vj.y;
            a2 += s2 * vj.x; c2 += s2 * vj.y;
            a3 += s3 * vj.x; c3 += s3 * vj.y;
        }
        float oa[4] = {a0, a1, a2, a3}, ob[4] = {c0, c1, c2, c3};
        #pragma unroll
        for (int a = 0; a < 4; a++) {
            size_t o = (size_t)(w * 64 + oi + a) * CC + h * 32 + d0;
            bfu hh, ll;
            splitf(oa[a], hh, ll); outH[o]     = hh; outL[o]     = ll;
            splitf(ob[a], hh, ll); outH[o + 1] = hh; outL[o + 1] = ll;
        }
    }
}

__global__ __launch_bounds__(256) void attn_kernel(
    const int* __restrict__ flag, const float* __restrict__ qkv,
    const void* __restrict__ rpb, bfu* __restrict__ outH, bfu* __restrict__ outL)
{
    if (*flag) attn_body<true >(qkv, rpb, outH, outL);
    else       attn_body<false>(qkv, rpb, outH, outL);
}

// ---------------- launch ----------------
extern "C" void kernel_launch(void* const* d_in, const int* in_sizes, int n_in,
                              void* d_out, int out_size, void* d_ws, size_t ws_size,
                              hipStream_t stream)
{
    const void* x      = d_in[0];
    const void* qkv_w  = d_in[1];
    const void* qkv_b  = d_in[2];
    const void* proj_w = d_in[3];
    const void* proj_b = d_in[4];
    const void* rpb    = d_in[5];
    const void* n1s    = d_in[6];
    const void* n1b    = d_in[7];
    const void* n2s    = d_in[8];
    const void* n2b    = d_in[9];
    const void* w1     = d_in[10];
    const void* b1     = d_in[11];
    const void* w2     = d_in[12];
    const void* b2     = d_in[13];

    // per-chunk intermediates: 3840 B/row (same as fp32 layout; split pairs == fp32 bytes)
    int nch = 1;
    while (nch < 128 && ((size_t)(MROWS / nch) * 3840 + 1024 + WBYTES) > ws_size) nch *= 2;
    const int R = MROWS / nch;

    int* flag = (int*)d_ws;
    bfu* wb   = (bfu*)((char*)d_ws + 1024);
    bfu* wqH = wb,          * wqL = wb + 110592;   // 576x192
    bfu* wpH = wb + 221184, * wpL = wb + 258048;   // 192x192
    bfu* w1H = wb + 294912, * w1L = wb + 442368;   // 768x192
    bfu* w2H = wb + 589824, * w2L = wb + 737280;   // 192x768
    bfu* fB  = wb + 884736;                        // chunk area (WBYTES/2 bfu)

    // phase 1 layout (bfu units): xwH/xwL R*192 each | qkvc fp32 R*576 | aoH/aoL R*192 each
    bfu*   xwH = fB;
    bfu*   xwL = fB + (size_t)R * 192;
    float* qkvc = (float*)(fB + (size_t)R * 384);
    bfu*   aoH = fB + (size_t)R * 384 + (size_t)R * 1152;
    bfu*   aoL = aoH + (size_t)R * 192;
    // phase 2 layout: xnH/xnL R*192 each | hbH/hbL R*768 each
    bfu*   xnH = fB;
    bfu*   xnL = fB + (size_t)R * 192;
    bfu*   hbH = fB + (size_t)R * 384;
    bfu*   hbL = hbH + (size_t)R * 768;

    detect_kernel<<<1, 256, 0, stream>>>(x, flag);
    prep_kernel<<<dim3(3, 576),  64, 0, stream>>>(flag, qkv_w,  wqH, wqL, 192, 576);
    prep_kernel<<<dim3(3, 192),  64, 0, stream>>>(flag, proj_w, wpH, wpL, 192, 192);
    prep_kernel<<<dim3(3, 768),  64, 0, stream>>>(flag, w1,     w1H, w1L, 192, 768);
    prep_kernel<<<dim3(12, 192), 64, 0, stream>>>(flag, w2,     w2H, w2L, 768, 192);

    // phase 1: LN1+shift+window -> qkv -> attn -> proj+unshift+residual(x) -> d_out
    for (int c = 0; c < nch; c++) {
        const int row0 = c * R;
        ln_kernel<true><<<R, 64, 0, stream>>>(flag, x, n1s, n1b, xwH, xwL, row0);
        gemm_kernel<0><<<dim3(C3 / 64, R / 128), 256, 0, stream>>>(
            flag, xwH, xwL, wqH, wqL, qkv_b, nullptr, qkvc, nullptr, CC, C3, 0);
        attn_kernel<<<(R / 64) * 6, 256, 0, stream>>>(flag, qkvc, rpb, aoH, aoL);
        gemm_kernel<1><<<dim3(CC / 64, R / 128), 256, 0, stream>>>(
            flag, aoH, aoL, wpH, wpL, proj_b, x, d_out, nullptr, CC, CC, row0);
    }

    // phase 2: LN2 -> mlp1+gelu -> mlp2+residual ; x2 lives in d_out (global rows)
    for (int c = 0; c < nch; c++) {
        const int row0 = c * R;
        ln_kernel<false><<<R, 64, 0, stream>>>(flag, d_out, n2s, n2b, xnH, xnL, row0);
        gemm_kernel<2><<<dim3(CM / 64, R / 128), 256, 0, stream>>>(
            flag, xnH, xnL, w1H, w1L, b1, nullptr, hbH, hbL, CC, CM, 0);
        gemm_kernel<3><<<dim3(CC / 64, R / 128), 256, 0, stream>>>(
            flag, hbH, hbL, w2H, w2L, b2, d_out, d_out, nullptr, CM, CC, row0);
    }
}

// Round 3
// 1090.667 us; speedup vs baseline: 1.8737x; 1.1599x over previous
//
#include <hip/hip_runtime.h>
#include <math.h>

typedef unsigned short bfu;
typedef __attribute__((ext_vector_type(4))) float  f32x4;
typedef __attribute__((ext_vector_type(8))) short  bf16x8;

// ---------- scalar bf16 helpers ----------
__device__ __forceinline__ float b2f(bfu v) { return __uint_as_float((unsigned)v << 16); }
__device__ __forceinline__ bfu f2b(float f) {
    unsigned u = __float_as_uint(f);
    u += 0x7fffu + ((u >> 16) & 1u);   // RNE
    return (bfu)(u >> 16);
}
__device__ __forceinline__ void splitf(float x, bfu& h, bfu& l) {
    h = f2b(x);
    l = f2b(x - b2f(h));
}
// runtime dtype-dual load/store (dual=1 -> fp32, dual=0 -> bf16)
__device__ __forceinline__ float ldgf(int dual, const void* p, size_t i) {
    return dual ? ((const float*)p)[i] : b2f(((const bfu*)p)[i]);
}
__device__ __forceinline__ void stgf(int dual, void* p, size_t i, float v) {
    if (dual) ((float*)p)[i] = v;
    else      ((bfu*)p)[i] = f2b(v);
}

// Problem constants
#define CC    192
#define C3P   640      // qkv columns padded 576 -> 640
#define CM    768
#define MROWS 131072   // 8*128*128
#define SHIFT 4
#define WBYTES 2064384 // split+transposed weight area (padded N)

// ---------------- dtype probe ----------------
__global__ void detect_kernel(const void* x, int* flag) {
    __shared__ int bad;
    if (threadIdx.x == 0) bad = 0;
    __syncthreads();
    int local = 0;
    for (int i = 0; i < 16; i++) {
        float v = b2f(((const bfu*)x)[threadIdx.x + i * 256]);
        if (!(fabsf(v) < 1000.0f)) local = 1;
    }
    if (local) atomicOr(&bad, 1);
    __syncthreads();
    if (threadIdx.x == 0) *flag = bad;          // 1 -> fp32, 0 -> bf16
}

// ---------------- weight prep: split + transpose (+ zero pad rows) ----------------
// dst[n][k] = split(W[k][n]) for n < Nreal, 0 otherwise. grid = (K/64, Npad).
__global__ __launch_bounds__(64) void prep_kernel(
    const int* __restrict__ flag, const void* __restrict__ w,
    bfu* __restrict__ dh, bfu* __restrict__ dl, int K, int Nreal)
{
    const int k = blockIdx.x * 64 + threadIdx.x;
    const int n = blockIdx.y;
    float v = 0.0f;
    if (n < Nreal)
        v = (*flag) ? ((const float*)w)[(size_t)k * Nreal + n]
                    : b2f(((const bfu*)w)[(size_t)k * Nreal + n]);
    bfu h, l;
    splitf(v, h, l);
    dh[(size_t)n * K + k] = h;
    dl[(size_t)n * K + k] = l;
}

// ---------------- LayerNorm -> single bf16 ----------------
template<bool REMAP, bool F32>
__device__ void ln_body(const void* x, const void* sc, const void* bi,
                        bfu* o, int row0)
{
    const int rg = row0 + blockIdx.x;
    size_t src;
    if (REMAP) {
        int w = rg >> 6, n = rg & 63;
        int b = w >> 8, wi = (w >> 4) & 15, wj = w & 15;
        int ii = wi * 8 + (n >> 3), jj = wj * 8 + (n & 7);
        int si = (ii + SHIFT) & 127, sj = (jj + SHIFT) & 127;
        src = (((size_t)b << 14) + ((size_t)si << 7) + sj) * CC;
    } else {
        src = (size_t)rg * CC;
    }
    const int t = threadIdx.x;
    float v0 = F32 ? ((const float*)x)[src + t]       : b2f(((const bfu*)x)[src + t]);
    float v1 = F32 ? ((const float*)x)[src + t + 64]  : b2f(((const bfu*)x)[src + t + 64]);
    float v2 = F32 ? ((const float*)x)[src + t + 128] : b2f(((const bfu*)x)[src + t + 128]);
    float sum = v0 + v1 + v2;
    float sq  = v0 * v0 + v1 * v1 + v2 * v2;
    #pragma unroll
    for (int off = 32; off > 0; off >>= 1) {
        sum += __shfl_xor(sum, off);
        sq  += __shfl_xor(sq, off);
    }
    float mu  = sum * (1.0f / 192.0f);
    float var = sq * (1.0f / 192.0f) - mu * mu;
    float rs  = rsqrtf(var + 1e-5f);
    size_t dst = (size_t)blockIdx.x * CC;
    const int dual = F32 ? 1 : 0;
    o[dst + t]       = f2b((v0 - mu) * rs * ldgf(dual, sc, t)       + ldgf(dual, bi, t));
    o[dst + t + 64]  = f2b((v1 - mu) * rs * ldgf(dual, sc, t + 64)  + ldgf(dual, bi, t + 64));
    o[dst + t + 128] = f2b((v2 - mu) * rs * ldgf(dual, sc, t + 128) + ldgf(dual, bi, t + 128));
}

template<bool REMAP>
__global__ __launch_bounds__(64) void ln_kernel(
    const int* __restrict__ flag, const void* __restrict__ x,
    const void* __restrict__ sc, const void* __restrict__ bi,
    bfu* __restrict__ o, int row0)
{
    if (*flag) ln_body<REMAP, true>(x, sc, bi, o, row0);
    else       ln_body<REMAP, false>(x, sc, bi, o, row0);
}

// ---------------- MFMA GEMM ----------------
// A: single bf16 [M][K] chunk-local. B: split+transposed (BhT,BlT) bf16 [Npad][K].
// acc = A*Bh (+ A*Bl if fp32 mode; in bf16 mode Bl == 0 exactly -> skipped).
// Tile: 128x128, BK=32, 4 waves (2x2), wave tile 64x64 = 4m x 4n of 16x16x32.
// MODE 0: -> bf16 out (qkvc, stride Nstr=640), chunk-local rows
// MODE 1: + inverse shift/window row map + residual(x dual) -> d_out dual
// MODE 2: + exact GELU -> bf16 out (mlp hidden), chunk-local
// MODE 3: + residual(d_out dual, global rows) -> d_out dual
template<int MODE>
__global__ __launch_bounds__(256) void gemm_kernel(
    const int* __restrict__ flag,
    const bfu* __restrict__ A,
    const bfu* __restrict__ BhT, const bfu* __restrict__ BlT,
    const void* __restrict__ bias, const void* __restrict__ res,
    void* __restrict__ out,
    int K, int Nstr, int Nreal, int row0)
{
    const int dual = *flag;
    __shared__ __align__(16) bfu As [128][40];
    __shared__ __align__(16) bfu BsH[128][40];
    __shared__ __align__(16) bfu BsL[128][40];
    const int t  = threadIdx.x;
    const int m0 = blockIdx.y * 128;
    const int n0 = blockIdx.x * 128;
    const int sr = t >> 1, sk = (t & 1) * 16;     // staging: row, k-offset (16 bfu each)
    const int l  = t & 63, wv = t >> 6;
    const int wm = wv >> 1, wn = wv & 1;          // 2x2 wave grid
    const int fr = l & 15, fk = (l >> 4) * 8;     // fragment row, k offset
    const int q4 = l >> 4;

    const bfu* gA = A   + (size_t)(m0 + sr) * K + sk;
    const bfu* gH = BhT + (size_t)(n0 + sr) * K + sk;
    const bfu* gL = BlT + (size_t)(n0 + sr) * K + sk;

    f32x4 acc[4][4];
    #pragma unroll
    for (int mt = 0; mt < 4; mt++)
        #pragma unroll
        for (int nt = 0; nt < 4; nt++)
            acc[mt][nt] = f32x4{0.f, 0.f, 0.f, 0.f};

    // software-pipelined staging registers
    f32x4 ra0 = *(const f32x4*)(gA);
    f32x4 ra1 = *(const f32x4*)(gA + 8);
    f32x4 rh0 = *(const f32x4*)(gH);
    f32x4 rh1 = *(const f32x4*)(gH + 8);
    f32x4 rl0 = f32x4{0.f, 0.f, 0.f, 0.f}, rl1 = rl0;
    if (dual) { rl0 = *(const f32x4*)(gL); rl1 = *(const f32x4*)(gL + 8); }

    for (int k0 = 0; k0 < K; k0 += 32) {
        __syncthreads();
        *(f32x4*)&As [sr][sk]     = ra0;
        *(f32x4*)&As [sr][sk + 8] = ra1;
        *(f32x4*)&BsH[sr][sk]     = rh0;
        *(f32x4*)&BsH[sr][sk + 8] = rh1;
        if (dual) {
            *(f32x4*)&BsL[sr][sk]     = rl0;
            *(f32x4*)&BsL[sr][sk + 8] = rl1;
        }
        __syncthreads();
        if (k0 + 32 < K) {   // issue next-tile loads; latency hides under MFMA
            ra0 = *(const f32x4*)(gA + k0 + 32);
            ra1 = *(const f32x4*)(gA + k0 + 40);
            rh0 = *(const f32x4*)(gH + k0 + 32);
            rh1 = *(const f32x4*)(gH + k0 + 40);
            if (dual) {
                rl0 = *(const f32x4*)(gL + k0 + 32);
                rl1 = *(const f32x4*)(gL + k0 + 40);
            }
        }
        bf16x8 af[4], bf[4];
        #pragma unroll
        for (int mt = 0; mt < 4; mt++)
            af[mt] = *(const bf16x8*)&As[wm * 64 + mt * 16 + fr][fk];
        #pragma unroll
        for (int nt = 0; nt < 4; nt++)
            bf[nt] = *(const bf16x8*)&BsH[wn * 64 + nt * 16 + fr][fk];
        #pragma unroll
        for (int mt = 0; mt < 4; mt++)
            #pragma unroll
            for (int nt = 0; nt < 4; nt++)
                acc[mt][nt] = __builtin_amdgcn_mfma_f32_16x16x32_bf16(af[mt], bf[nt], acc[mt][nt], 0, 0, 0);
        if (dual) {
            bf16x8 bl[4];
            #pragma unroll
            for (int nt = 0; nt < 4; nt++)
                bl[nt] = *(const bf16x8*)&BsL[wn * 64 + nt * 16 + fr][fk];
            #pragma unroll
            for (int mt = 0; mt < 4; mt++)
                #pragma unroll
                for (int nt = 0; nt < 4; nt++)
                    acc[mt][nt] = __builtin_amdgcn_mfma_f32_16x16x32_bf16(af[mt], bl[nt], acc[mt][nt], 0, 0, 0);
        }
    }

    float bia[4];
    #pragma unroll
    for (int nt = 0; nt < 4; nt++) {
        int col = n0 + wn * 64 + nt * 16 + fr;
        bia[nt] = (col < Nreal) ? ldgf(dual, bias, col) : 0.0f;
    }

    #pragma unroll
    for (int mt = 0; mt < 4; mt++) {
        #pragma unroll
        for (int r = 0; r < 4; r++) {
            const int rl = m0 + wm * 64 + mt * 16 + q4 * 4 + r;
            size_t orow;
            if (MODE == 1) {
                int rg = row0 + rl;
                int w = rg >> 6, n = rg & 63;
                int b_ = w >> 8, wi = (w >> 4) & 15, wj = w & 15;
                int ii = wi * 8 + (n >> 3), jj = wj * 8 + (n & 7);
                int fi = (ii + SHIFT) & 127, fj = (jj + SHIFT) & 127;
                orow = ((size_t)b_ << 14) + ((size_t)fi << 7) + fj;
            } else if (MODE == 3) {
                orow = (size_t)(row0 + rl);
            } else {
                orow = (size_t)rl;
            }
            #pragma unroll
            for (int nt = 0; nt < 4; nt++) {
                int col = n0 + wn * 64 + nt * 16 + fr;
                if ((MODE == 1 || MODE == 3) && col >= Nreal) continue;
                size_t o = orow * Nstr + col;
                float v = acc[mt][nt][r] + bia[nt];
                if (MODE == 1 || MODE == 3) {
                    v += ldgf(dual, res, o);
                    stgf(dual, out, o, v);
                } else if (MODE == 2) {
                    v = v * 0.5f * (1.0f + erff(v * 0.70710678118654752f));
                    ((bfu*)out)[o] = f2b(v);
                } else {
                    ((bfu*)out)[o] = f2b(v);
                }
            }
        }
    }
}

// ---------------- Windowed attention (bf16 qkv in, bf16 out) ----------------
__global__ __launch_bounds__(256) void attn_kernel(
    const int* __restrict__ flag, const bfu* __restrict__ qkv,
    const void* __restrict__ rpb, bfu* __restrict__ outp)
{
    const int dual = *flag;
    __shared__ __align__(16) float qT[32][64];
    __shared__ __align__(16) float kT[32][64];
    __shared__ __align__(16) float vsm[64][32];
    __shared__ __align__(16) float S[64][68];
    __shared__ float bias_s[225 * 6];
    const int t = threadIdx.x;
    const int w = blockIdx.x / 6;
    const int h = blockIdx.x % 6;

    if (dual) { for (int i = t; i < 1350; i += 256) bias_s[i] = ((const float*)rpb)[i]; }
    else      { for (int i = t; i < 1350; i += 256) bias_s[i] = b2f(((const bfu*)rpb)[i]); }
    {
        const int n = t >> 2, d0 = (t & 3) * 8;
        size_t base = (size_t)(w * 64 + n) * C3P + h * 32 + d0;
        bf16x8 vq = *(const bf16x8*)&qkv[base];
        bf16x8 vk = *(const bf16x8*)&qkv[base + 192];
        bf16x8 vv = *(const bf16x8*)&qkv[base + 384];
        #pragma unroll
        for (int i = 0; i < 8; i++) {
            qT[d0 + i][n]  = b2f((bfu)vq[i]);
            kT[d0 + i][n]  = b2f((bfu)vk[i]);
            vsm[n][d0 + i] = b2f((bfu)vv[i]);
        }
    }
    __syncthreads();

    {
        const int i0 = (t >> 4) * 4, j0 = (t & 15) * 4;
        float sacc[4][4] = {};
        #pragma unroll
        for (int kk = 0; kk < 32; kk++) {
            float4 q4 = *reinterpret_cast<float4*>(&qT[kk][i0]);
            float4 k4 = *reinterpret_cast<float4*>(&kT[kk][j0]);
            float qa[4] = {q4.x, q4.y, q4.z, q4.w};
            float kb[4] = {k4.x, k4.y, k4.z, k4.w};
            #pragma unroll
            for (int a = 0; a < 4; a++)
                #pragma unroll
                for (int b = 0; b < 4; b++)
                    sacc[a][b] += qa[a] * kb[b];
        }
        #pragma unroll
        for (int a = 0; a < 4; a++) {
            int i = i0 + a;
            #pragma unroll
            for (int b = 0; b < 4; b++) {
                int j = j0 + b;
                int rel = ((i >> 3) - (j >> 3) + 7) * 15 + ((i & 7) - (j & 7) + 7);
                S[i][j] = sacc[a][b] * 0.17677669529663687f + bias_s[rel * 6 + h];
            }
        }
    }
    __syncthreads();

    {
        const int r = t >> 2, q = (t & 3) * 16;
        float mx = -1e30f;
        #pragma unroll
        for (int j = 0; j < 16; j++) mx = fmaxf(mx, S[r][q + j]);
        mx = fmaxf(mx, __shfl_xor(mx, 1));
        mx = fmaxf(mx, __shfl_xor(mx, 2));
        float sm = 0.f;
        #pragma unroll
        for (int j = 0; j < 16; j++) { float e = __expf(S[r][q + j] - mx); S[r][q + j] = e; sm += e; }
        sm += __shfl_xor(sm, 1);
        sm += __shfl_xor(sm, 2);
        float inv = 1.0f / sm;
        #pragma unroll
        for (int j = 0; j < 16; j++) S[r][q + j] *= inv;
    }
    __syncthreads();

    {
        const int oi = (t >> 4) * 4, d0 = (t & 15) * 2;
        float a0 = 0, a1 = 0, a2 = 0, a3 = 0, c0 = 0, c1 = 0, c2 = 0, c3 = 0;
        for (int j = 0; j < 64; j++) {
            float2 vj = *reinterpret_cast<float2*>(&vsm[j][d0]);
            float s0 = S[oi][j], s1 = S[oi + 1][j], s2 = S[oi + 2][j], s3 = S[oi + 3][j];
            a0 += s0 * vj.x; c0 += s0 * vj.y;
            a1 += s1 * vj.x; c1 += s1 * vj.y;
            a2 += s2 * vj.x; c2 += s2 * vj.y;
            a3 += s3 * vj.x; c3 += s3 * vj.y;
        }
        float oa[4] = {a0, a1, a2, a3}, ob[4] = {c0, c1, c2, c3};
        #pragma unroll
        for (int a = 0; a < 4; a++) {
            size_t o = (size_t)(w * 64 + oi + a) * CC + h * 32 + d0;
            unsigned pk = (unsigned)f2b(oa[a]) | ((unsigned)f2b(ob[a]) << 16);
            *(unsigned*)&outp[o] = pk;
        }
    }
}

// ---------------- launch ----------------
extern "C" void kernel_launch(void* const* d_in, const int* in_sizes, int n_in,
                              void* d_out, int out_size, void* d_ws, size_t ws_size,
                              hipStream_t stream)
{
    const void* x      = d_in[0];
    const void* qkv_w  = d_in[1];
    const void* qkv_b  = d_in[2];
    const void* proj_w = d_in[3];
    const void* proj_b = d_in[4];
    const void* rpb    = d_in[5];
    const void* n1s    = d_in[6];
    const void* n1b    = d_in[7];
    const void* n2s    = d_in[8];
    const void* n2b    = d_in[9];
    const void* w1     = d_in[10];
    const void* b1     = d_in[11];
    const void* w2     = d_in[12];
    const void* b2     = d_in[13];

    // per-chunk intermediates: 2048 B/row (phase1: xw 384 + qkvc 1280 + ao 384)
    int nch = 1;
    while (nch < 128 && ((size_t)(MROWS / nch) * 2048 + 1024 + WBYTES) > ws_size) nch *= 2;
    const int R = MROWS / nch;

    int* flag = (int*)d_ws;
    bfu* wb   = (bfu*)((char*)d_ws + 1024);
    // weight areas (bfu offsets): qkv 640x192, proj 256x192, w1 768x192, w2 256x768
    bfu* wqH = wb;           bfu* wqL = wb + 122880;
    bfu* wpH = wb + 245760;  bfu* wpL = wb + 294912;
    bfu* w1H = wb + 344064;  bfu* w1L = wb + 491520;
    bfu* w2H = wb + 638976;  bfu* w2L = wb + 835584;
    bfu* fB  = wb + 1032192;                       // chunk area

    // phase 1 layout (bfu units): xw R*192 | qkvc R*640 | ao R*192
    bfu* xw   = fB;
    bfu* qkvc = fB + (size_t)R * 192;
    bfu* ao   = fB + (size_t)R * 832;
    // phase 2 layout: xn R*192 | hb R*768
    bfu* xn   = fB;
    bfu* hb   = fB + (size_t)R * 192;

    detect_kernel<<<1, 256, 0, stream>>>(x, flag);
    prep_kernel<<<dim3(3, 640),  64, 0, stream>>>(flag, qkv_w,  wqH, wqL, 192, 576);
    prep_kernel<<<dim3(3, 256),  64, 0, stream>>>(flag, proj_w, wpH, wpL, 192, 192);
    prep_kernel<<<dim3(3, 768),  64, 0, stream>>>(flag, w1,     w1H, w1L, 192, 768);
    prep_kernel<<<dim3(12, 256), 64, 0, stream>>>(flag, w2,     w2H, w2L, 768, 192);

    // phase 1: LN1+shift+window -> qkv -> attn -> proj+unshift+residual(x) -> d_out
    for (int c = 0; c < nch; c++) {
        const int row0 = c * R;
        ln_kernel<true><<<R, 64, 0, stream>>>(flag, x, n1s, n1b, xw, row0);
        gemm_kernel<0><<<dim3(5, R / 128), 256, 0, stream>>>(
            flag, xw, wqH, wqL, qkv_b, nullptr, qkvc, 192, C3P, 576, 0);
        attn_kernel<<<(R / 64) * 6, 256, 0, stream>>>(flag, qkvc, rpb, ao);
        gemm_kernel<1><<<dim3(2, R / 128), 256, 0, stream>>>(
            flag, ao, wpH, wpL, proj_b, x, d_out, 192, CC, CC, row0);
    }

    // phase 2: LN2 -> mlp1+gelu -> mlp2+residual ; x2 lives in d_out (global rows)
    for (int c = 0; c < nch; c++) {
        const int row0 = c * R;
        ln_kernel<false><<<R, 64, 0, stream>>>(flag, d_out, n2s, n2b, xn, row0);
        gemm_kernel<2><<<dim3(6, R / 128), 256, 0, stream>>>(
            flag, xn, w1H, w1L, b1, nullptr, hb, 192, CM, CM, 0);
        gemm_kernel<3><<<dim3(2, R / 128), 256, 0, stream>>>(
            flag, hb, w2H, w2L, b2, d_out, d_out, 768, CC, CC, row0);
    }
}

// Round 5
// 1090.085 us; speedup vs baseline: 1.8748x; 1.0005x over previous
//
#include <hip/hip_runtime.h>
#include <math.h>

typedef unsigned short bfu;
typedef __attribute__((ext_vector_type(4))) float  f32x4;
typedef __attribute__((ext_vector_type(8))) short  bf16x8;

// ---------- scalar bf16 helpers ----------
__device__ __forceinline__ float b2f(bfu v) { return __uint_as_float((unsigned)v << 16); }
__device__ __forceinline__ bfu f2b(float f) {
    unsigned u = __float_as_uint(f);
    u += 0x7fffu + ((u >> 16) & 1u);   // RNE
    return (bfu)(u >> 16);
}
__device__ __forceinline__ void splitf(float x, bfu& h, bfu& l) {
    h = f2b(x);
    l = f2b(x - b2f(h));
}
// runtime dtype-dual load/store (dual=1 -> fp32, dual=0 -> bf16)
__device__ __forceinline__ float ldgf(int dual, const void* p, size_t i) {
    return dual ? ((const float*)p)[i] : b2f(((const bfu*)p)[i]);
}
__device__ __forceinline__ void stgf(int dual, void* p, size_t i, float v) {
    if (dual) ((float*)p)[i] = v;
    else      ((bfu*)p)[i] = f2b(v);
}
// async global->LDS, 16B per lane; LDS dest = wave-uniform base + lane*16
__device__ __forceinline__ void gload16(const bfu* g, bfu* lds) {
    __builtin_amdgcn_global_load_lds((const __attribute__((address_space(1))) void*)g,
                                     (__attribute__((address_space(3))) void*)lds,
                                     16, 0, 0);
}

// Problem constants
#define CC    192
#define C3P   640      // qkv columns padded 576 -> 640
#define CM    768
#define MROWS 131072   // 8*128*128
#define SHIFT 4
#define WBYTES 2064384 // split+transposed weight area (padded N)

// ---------------- dtype probe ----------------
__global__ void detect_kernel(const void* x, int* flag) {
    __shared__ int bad;
    if (threadIdx.x == 0) bad = 0;
    __syncthreads();
    int local = 0;
    for (int i = 0; i < 16; i++) {
        float v = b2f(((const bfu*)x)[threadIdx.x + i * 256]);
        if (!(fabsf(v) < 1000.0f)) local = 1;
    }
    if (local) atomicOr(&bad, 1);
    __syncthreads();
    if (threadIdx.x == 0) *flag = bad;          // 1 -> fp32, 0 -> bf16
}

// ---------------- weight prep: split + transpose (+ zero pad rows) ----------------
__global__ __launch_bounds__(64) void prep_kernel(
    const int* __restrict__ flag, const void* __restrict__ w,
    bfu* __restrict__ dh, bfu* __restrict__ dl, int K, int Nreal)
{
    const int k = blockIdx.x * 64 + threadIdx.x;
    const int n = blockIdx.y;
    float v = 0.0f;
    if (n < Nreal)
        v = (*flag) ? ((const float*)w)[(size_t)k * Nreal + n]
                    : b2f(((const bfu*)w)[(size_t)k * Nreal + n]);
    bfu h, l;
    splitf(v, h, l);
    dh[(size_t)n * K + k] = h;
    dl[(size_t)n * K + k] = l;
}

// ---------------- LayerNorm -> single bf16 ----------------
template<bool REMAP, bool F32>
__device__ void ln_body(const void* x, const void* sc, const void* bi,
                        bfu* o, int row0)
{
    const int rg = row0 + blockIdx.x;
    size_t src;
    if (REMAP) {
        int w = rg >> 6, n = rg & 63;
        int b = w >> 8, wi = (w >> 4) & 15, wj = w & 15;
        int ii = wi * 8 + (n >> 3), jj = wj * 8 + (n & 7);
        int si = (ii + SHIFT) & 127, sj = (jj + SHIFT) & 127;
        src = (((size_t)b << 14) + ((size_t)si << 7) + sj) * CC;
    } else {
        src = (size_t)rg * CC;
    }
    const int t = threadIdx.x;
    float v0 = F32 ? ((const float*)x)[src + t]       : b2f(((const bfu*)x)[src + t]);
    float v1 = F32 ? ((const float*)x)[src + t + 64]  : b2f(((const bfu*)x)[src + t + 64]);
    float v2 = F32 ? ((const float*)x)[src + t + 128] : b2f(((const bfu*)x)[src + t + 128]);
    float sum = v0 + v1 + v2;
    float sq  = v0 * v0 + v1 * v1 + v2 * v2;
    #pragma unroll
    for (int off = 32; off > 0; off >>= 1) {
        sum += __shfl_xor(sum, off);
        sq  += __shfl_xor(sq, off);
    }
    float mu  = sum * (1.0f / 192.0f);
    float var = sq * (1.0f / 192.0f) - mu * mu;
    float rs  = rsqrtf(var + 1e-5f);
    size_t dst = (size_t)blockIdx.x * CC;
    const int dual = F32 ? 1 : 0;
    o[dst + t]       = f2b((v0 - mu) * rs * ldgf(dual, sc, t)       + ldgf(dual, bi, t));
    o[dst + t + 64]  = f2b((v1 - mu) * rs * ldgf(dual, sc, t + 64)  + ldgf(dual, bi, t + 64));
    o[dst + t + 128] = f2b((v2 - mu) * rs * ldgf(dual, sc, t + 128) + ldgf(dual, bi, t + 128));
}

template<bool REMAP>
__global__ __launch_bounds__(64) void ln_kernel(
    const int* __restrict__ flag, const void* __restrict__ x,
    const void* __restrict__ sc, const void* __restrict__ bi,
    bfu* __restrict__ o, int row0)
{
    if (*flag) ln_body<REMAP, true>(x, sc, bi, o, row0);
    else       ln_body<REMAP, false>(x, sc, bi, o, row0);
}

// ---------------- MFMA GEMM (global_load_lds + dbuf + swizzled LDS) ----------------
// A: single bf16 [M][K] chunk-local. B: split+transposed (BhT,BlT) bf16 [Npad][K].
// acc = A*Bh (+ A*Bl if fp32 mode; bf16 mode Bl==0 -> skipped).
// Tile 128x128, BK=32, 4 waves (2x2), wave tile 64x64 = 4m x 4n of 16x16x32.
// LDS: linear dest (global_load_lds), swizzled global src + swizzled read:
//   phys16Bslot = logical_j ^ ((row>>1)&3)  -> ds_read_b128 2-way (free).
template<int MODE>
__global__ __launch_bounds__(256) void gemm_kernel(
    const int* __restrict__ flag,
    const bfu* __restrict__ A,
    const bfu* __restrict__ BhT, const bfu* __restrict__ BlT,
    const void* __restrict__ bias, const void* __restrict__ res,
    void* __restrict__ out,
    int K, int Nstr, int Nreal, int row0)
{
    const int dual = *flag;
    __shared__ __align__(16) bfu As [2][4096];   // [buf][128 rows * 32 k]
    __shared__ __align__(16) bfu BsH[2][4096];
    __shared__ __align__(16) bfu BsL[2][4096];
    const int t  = threadIdx.x;
    const int m0 = blockIdx.y * 128;
    const int n0 = blockIdx.x * 128;
    const int l  = t & 63, wv = t >> 6;
    const int wm = wv >> 1, wn = wv & 1;          // 2x2 wave grid
    const int fr = l & 15, j = l >> 4;            // fragment row, 16B slot
    const int q4 = l >> 4;

    // staging geometry: wave wv covers rows 32*wv..32*wv+31 (2 issues of 16 rows)
    const int srow = (l >> 2);                    // 0..15 within issue
    const int slot = (l & 3) ^ ((l >> 3) & 3);    // swizzled k-slot (involution)

    f32x4 acc[4][4];
    #pragma unroll
    for (int mt = 0; mt < 4; mt++)
        #pragma unroll
        for (int nt = 0; nt < 4; nt++)
            acc[mt][nt] = f32x4{0.f, 0.f, 0.f, 0.f};

    #define STAGE(buf, kk)                                                        \
        do {                                                                      \
            _Pragma("unroll")                                                     \
            for (int i = 0; i < 2; i++) {                                         \
                const int r0 = wv * 32 + 16 * i;                                  \
                const int rw = r0 + srow;                                         \
                gload16(A   + (size_t)(m0 + rw) * K + (kk) + slot * 8,            \
                        &As [buf][r0 * 32]);                                      \
                gload16(BhT + (size_t)(n0 + rw) * K + (kk) + slot * 8,            \
                        &BsH[buf][r0 * 32]);                                      \
                if (dual)                                                         \
                    gload16(BlT + (size_t)(n0 + rw) * K + (kk) + slot * 8,        \
                            &BsL[buf][r0 * 32]);                                  \
            }                                                                     \
        } while (0)

    STAGE(0, 0);
    __syncthreads();                 // drain prologue loads (vmcnt0) + barrier

    int cur = 0;
    for (int k0 = 0; k0 < K; k0 += 32) {
        if (k0 + 32 < K) STAGE(cur ^ 1, k0 + 32);   // async, overlaps MFMA below

        bf16x8 af[4], bh[4];
        #pragma unroll
        for (int mt = 0; mt < 4; mt++) {
            const int row = wm * 64 + mt * 16 + fr;
            const int ph  = j ^ ((row >> 1) & 3);
            af[mt] = *(const bf16x8*)&As[cur][row * 32 + ph * 8];
        }
        #pragma unroll
        for (int nt = 0; nt < 4; nt++) {
            const int row = wn * 64 + nt * 16 + fr;
            const int ph  = j ^ ((row >> 1) & 3);
            bh[nt] = *(const bf16x8*)&BsH[cur][row * 32 + ph * 8];
        }
        #pragma unroll
        for (int mt = 0; mt < 4; mt++)
            #pragma unroll
            for (int nt = 0; nt < 4; nt++)
                acc[mt][nt] = __builtin_amdgcn_mfma_f32_16x16x32_bf16(af[mt], bh[nt], acc[mt][nt], 0, 0, 0);
        if (dual) {
            bf16x8 bl[4];
            #pragma unroll
            for (int nt = 0; nt < 4; nt++) {
                const int row = wn * 64 + nt * 16 + fr;
                const int ph  = j ^ ((row >> 1) & 3);
                bl[nt] = *(const bf16x8*)&BsL[cur][row * 32 + ph * 8];
            }
            #pragma unroll
            for (int mt = 0; mt < 4; mt++)
                #pragma unroll
                for (int nt = 0; nt < 4; nt++)
                    acc[mt][nt] = __builtin_amdgcn_mfma_f32_16x16x32_bf16(af[mt], bl[nt], acc[mt][nt], 0, 0, 0);
        }
        __syncthreads();             // vmcnt(0): next buf landed; barrier: WAR-safe
        cur ^= 1;
    }
    #undef STAGE

    float bia[4];
    #pragma unroll
    for (int nt = 0; nt < 4; nt++) {
        int col = n0 + wn * 64 + nt * 16 + fr;
        bia[nt] = (col < Nreal) ? ldgf(dual, bias, col) : 0.0f;
    }

    #pragma unroll
    for (int mt = 0; mt < 4; mt++) {
        #pragma unroll
        for (int r = 0; r < 4; r++) {
            const int rl = m0 + wm * 64 + mt * 16 + q4 * 4 + r;
            size_t orow;
            if (MODE == 1) {
                int rg = row0 + rl;
                int w = rg >> 6, n = rg & 63;
                int b_ = w >> 8, wi = (w >> 4) & 15, wj = w & 15;
                int ii = wi * 8 + (n >> 3), jj = wj * 8 + (n & 7);
                int fi = (ii + SHIFT) & 127, fj = (jj + SHIFT) & 127;
                orow = ((size_t)b_ << 14) + ((size_t)fi << 7) + fj;
            } else if (MODE == 3) {
                orow = (size_t)(row0 + rl);
            } else {
                orow = (size_t)rl;
            }
            #pragma unroll
            for (int nt = 0; nt < 4; nt++) {
                int col = n0 + wn * 64 + nt * 16 + fr;
                if ((MODE == 1 || MODE == 3) && col >= Nreal) continue;
                size_t o = orow * Nstr + col;
                float v = acc[mt][nt][r] + bia[nt];
                if (MODE == 1 || MODE == 3) {
                    v += ldgf(dual, res, o);
                    stgf(dual, out, o, v);
                } else if (MODE == 2) {
                    v = v * 0.5f * (1.0f + erff(v * 0.70710678118654752f));
                    ((bfu*)out)[o] = f2b(v);
                } else {
                    ((bfu*)out)[o] = f2b(v);
                }
            }
        }
    }
}

// ---------------- Windowed attention (bf16 qkv in, bf16 out) ----------------
__global__ __launch_bounds__(256) void attn_kernel(
    const int* __restrict__ flag, const bfu* __restrict__ qkv,
    const void* __restrict__ rpb, bfu* __restrict__ outp)
{
    const int dual = *flag;
    __shared__ __align__(16) float qT[32][64];
    __shared__ __align__(16) float kT[32][64];
    __shared__ __align__(16) float vsm[64][32];
    __shared__ __align__(16) float S[64][68];
    __shared__ float bias_s[225 * 6];
    const int t = threadIdx.x;
    const int w = blockIdx.x / 6;
    const int h = blockIdx.x % 6;

    if (dual) { for (int i = t; i < 1350; i += 256) bias_s[i] = ((const float*)rpb)[i]; }
    else      { for (int i = t; i < 1350; i += 256) bias_s[i] = b2f(((const bfu*)rpb)[i]); }
    {
        const int n = t >> 2, d0 = (t & 3) * 8;
        size_t base = (size_t)(w * 64 + n) * C3P + h * 32 + d0;
        bf16x8 vq = *(const bf16x8*)&qkv[base];
        bf16x8 vk = *(const bf16x8*)&qkv[base + 192];
        bf16x8 vv = *(const bf16x8*)&qkv[base + 384];
        #pragma unroll
        for (int i = 0; i < 8; i++) {
            qT[d0 + i][n]  = b2f((bfu)vq[i]);
            kT[d0 + i][n]  = b2f((bfu)vk[i]);
            vsm[n][d0 + i] = b2f((bfu)vv[i]);
        }
    }
    __syncthreads();

    {
        const int i0 = (t >> 4) * 4, j0 = (t & 15) * 4;
        float sacc[4][4] = {};
        #pragma unroll
        for (int kk = 0; kk < 32; kk++) {
            float4 q4 = *reinterpret_cast<float4*>(&qT[kk][i0]);
            float4 k4 = *reinterpret_cast<float4*>(&kT[kk][j0]);
            float qa[4] = {q4.x, q4.y, q4.z, q4.w};
            float kb[4] = {k4.x, k4.y, k4.z, k4.w};
            #pragma unroll
            for (int a = 0; a < 4; a++)
                #pragma unroll
                for (int b = 0; b < 4; b++)
                    sacc[a][b] += qa[a] * kb[b];
        }
        #pragma unroll
        for (int a = 0; a < 4; a++) {
            int i = i0 + a;
            #pragma unroll
            for (int b = 0; b < 4; b++) {
                int j = j0 + b;
                int rel = ((i >> 3) - (j >> 3) + 7) * 15 + ((i & 7) - (j & 7) + 7);
                S[i][j] = sacc[a][b] * 0.17677669529663687f + bias_s[rel * 6 + h];
            }
        }
    }
    __syncthreads();

    {
        const int r = t >> 2, q = (t & 3) * 16;
        float mx = -1e30f;
        #pragma unroll
        for (int j = 0; j < 16; j++) mx = fmaxf(mx, S[r][q + j]);
        mx = fmaxf(mx, __shfl_xor(mx, 1));
        mx = fmaxf(mx, __shfl_xor(mx, 2));
        float sm = 0.f;
        #pragma unroll
        for (int j = 0; j < 16; j++) { float e = __expf(S[r][q + j] - mx); S[r][q + j] = e; sm += e; }
        sm += __shfl_xor(sm, 1);
        sm += __shfl_xor(sm, 2);
        float inv = 1.0f / sm;
        #pragma unroll
        for (int j = 0; j < 16; j++) S[r][q + j] *= inv;
    }
    __syncthreads();

    {
        const int oi = (t >> 4) * 4, d0 = (t & 15) * 2;
        float a0 = 0, a1 = 0, a2 = 0, a3 = 0, c0 = 0, c1 = 0, c2 = 0, c3 = 0;
        for (int j = 0; j < 64; j++) {
            float2 vj = *reinterpret_cast<float2*>(&vsm[j][d0]);
            float s0 = S[oi][j], s1 = S[oi + 1][j], s2 = S[oi + 2][j], s3 = S[oi + 3][j];
            a0 += s0 * vj.x; c0 += s0 * vj.y;
            a1 += s1 * vj.x; c1 += s1 * vj.y;
            a2 += s2 * vj.x; c2 += s2 * vj.y;
            a3 += s3 * vj.x; c3 += s3 * vj.y;
        }
        float oa[4] = {a0, a1, a2, a3}, ob[4] = {c0, c1, c2, c3};
        #pragma unroll
        for (int a = 0; a < 4; a++) {
            size_t o = (size_t)(w * 64 + oi + a) * CC + h * 32 + d0;
            unsigned pk = (unsigned)f2b(oa[a]) | ((unsigned)f2b(ob[a]) << 16);
            *(unsigned*)&outp[o] = pk;
        }
    }
}

// ---------------- launch ----------------
extern "C" void kernel_launch(void* const* d_in, const int* in_sizes, int n_in,
                              void* d_out, int out_size, void* d_ws, size_t ws_size,
                              hipStream_t stream)
{
    const void* x      = d_in[0];
    const void* qkv_w  = d_in[1];
    const void* qkv_b  = d_in[2];
    const void* proj_w = d_in[3];
    const void* proj_b = d_in[4];
    const void* rpb    = d_in[5];
    const void* n1s    = d_in[6];
    const void* n1b    = d_in[7];
    const void* n2s    = d_in[8];
    const void* n2b    = d_in[9];
    const void* w1     = d_in[10];
    const void* b1     = d_in[11];
    const void* w2     = d_in[12];
    const void* b2     = d_in[13];

    // per-chunk intermediates: 2048 B/row (phase1: xw 384 + qkvc 1280 + ao 384)
    int nch = 1;
    while (nch < 128 && ((size_t)(MROWS / nch) * 2048 + 1024 + WBYTES) > ws_size) nch *= 2;
    const int R = MROWS / nch;

    int* flag = (int*)d_ws;
    bfu* wb   = (bfu*)((char*)d_ws + 1024);
    // weight areas (bfu offsets): qkv 640x192, proj 256x192, w1 768x192, w2 256x768
    bfu* wqH = wb;           bfu* wqL = wb + 122880;
    bfu* wpH = wb + 245760;  bfu* wpL = wb + 294912;
    bfu* w1H = wb + 344064;  bfu* w1L = wb + 491520;
    bfu* w2H = wb + 638976;  bfu* w2L = wb + 835584;
    bfu* fB  = wb + 1032192;                       // chunk area

    // phase 1 layout (bfu units): xw R*192 | qkvc R*640 | ao R*192
    bfu* xw   = fB;
    bfu* qkvc = fB + (size_t)R * 192;
    bfu* ao   = fB + (size_t)R * 832;
    // phase 2 layout: xn R*192 | hb R*768
    bfu* xn   = fB;
    bfu* hb   = fB + (size_t)R * 192;

    detect_kernel<<<1, 256, 0, stream>>>(x, flag);
    prep_kernel<<<dim3(3, 640),  64, 0, stream>>>(flag, qkv_w,  wqH, wqL, 192, 576);
    prep_kernel<<<dim3(3, 256),  64, 0, stream>>>(flag, proj_w, wpH, wpL, 192, 192);
    prep_kernel<<<dim3(3, 768),  64, 0, stream>>>(flag, w1,     w1H, w1L, 192, 768);
    prep_kernel<<<dim3(12, 256), 64, 0, stream>>>(flag, w2,     w2H, w2L, 768, 192);

    // phase 1: LN1+shift+window -> qkv -> attn -> proj+unshift+residual(x) -> d_out
    for (int c = 0; c < nch; c++) {
        const int row0 = c * R;
        ln_kernel<true><<<R, 64, 0, stream>>>(flag, x, n1s, n1b, xw, row0);
        gemm_kernel<0><<<dim3(5, R / 128), 256, 0, stream>>>(
            flag, xw, wqH, wqL, qkv_b, nullptr, qkvc, 192, C3P, 576, 0);
        attn_kernel<<<(R / 64) * 6, 256, 0, stream>>>(flag, qkvc, rpb, ao);
        gemm_kernel<1><<<dim3(2, R / 128), 256, 0, stream>>>(
            flag, ao, wpH, wpL, proj_b, x, d_out, 192, CC, CC, row0);
    }

    // phase 2: LN2 -> mlp1+gelu -> mlp2+residual ; x2 lives in d_out (global rows)
    for (int c = 0; c < nch; c++) {
        const int row0 = c * R;
        ln_kernel<false><<<R, 64, 0, stream>>>(flag, d_out, n2s, n2b, xn, row0);
        gemm_kernel<2><<<dim3(6, R / 128), 256, 0, stream>>>(
            flag, xn, w1H, w1L, b1, nullptr, hb, 192, CM, CM, 0);
        gemm_kernel<3><<<dim3(2, R / 128), 256, 0, stream>>>(
            flag, hb, w2H, w2L, b2, d_out, d_out, 768, CC, CC, row0);
    }
}

// Round 6
// 1052.488 us; speedup vs baseline: 1.9417x; 1.0357x over previous
//
#include <hip/hip_runtime.h>
#include <math.h>

typedef unsigned short bfu;
typedef __attribute__((ext_vector_type(4))) float  f32x4;
typedef __attribute__((ext_vector_type(8))) short  bf16x8;

// ---------- scalar bf16 helpers ----------
__device__ __forceinline__ float b2f(bfu v) { return __uint_as_float((unsigned)v << 16); }
__device__ __forceinline__ bfu f2b(float f) {
    unsigned u = __float_as_uint(f);
    u += 0x7fffu + ((u >> 16) & 1u);   // RNE
    return (bfu)(u >> 16);
}
__device__ __forceinline__ void splitf(float x, bfu& h, bfu& l) {
    h = f2b(x);
    l = f2b(x - b2f(h));
}
// runtime dtype-dual load/store (dual=1 -> fp32, dual=0 -> bf16)
__device__ __forceinline__ float ldgf(int dual, const void* p, size_t i) {
    return dual ? ((const float*)p)[i] : b2f(((const bfu*)p)[i]);
}
__device__ __forceinline__ void stgf(int dual, void* p, size_t i, float v) {
    if (dual) ((float*)p)[i] = v;
    else      ((bfu*)p)[i] = f2b(v);
}
// async global->LDS, 16B per lane; LDS dest = wave-uniform base + lane*16
__device__ __forceinline__ void gload16(const bfu* g, bfu* lds) {
    __builtin_amdgcn_global_load_lds((const __attribute__((address_space(1))) void*)g,
                                     (__attribute__((address_space(3))) void*)lds,
                                     16, 0, 0);
}

// Problem constants
#define CC    192
#define C3P   640      // qkv columns padded 576 -> 640
#define CM    768
#define MROWS 131072   // 8*128*128
#define SHIFT 4
#define WBYTES 2064384 // split+transposed weight area (padded N)

// ---------------- dtype probe ----------------
__global__ void detect_kernel(const void* x, int* flag) {
    __shared__ int bad;
    if (threadIdx.x == 0) bad = 0;
    __syncthreads();
    int local = 0;
    for (int i = 0; i < 16; i++) {
        float v = b2f(((const bfu*)x)[threadIdx.x + i * 256]);
        if (!(fabsf(v) < 1000.0f)) local = 1;
    }
    if (local) atomicOr(&bad, 1);
    __syncthreads();
    if (threadIdx.x == 0) *flag = bad;          // 1 -> fp32, 0 -> bf16
}

// ---------------- weight prep: split + transpose (+ zero pad rows) ----------------
__global__ __launch_bounds__(64) void prep_kernel(
    const int* __restrict__ flag, const void* __restrict__ w,
    bfu* __restrict__ dh, bfu* __restrict__ dl, int K, int Nreal)
{
    const int k = blockIdx.x * 64 + threadIdx.x;
    const int n = blockIdx.y;
    float v = 0.0f;
    if (n < Nreal)
        v = (*flag) ? ((const float*)w)[(size_t)k * Nreal + n]
                    : b2f(((const bfu*)w)[(size_t)k * Nreal + n]);
    bfu h, l;
    splitf(v, h, l);
    dh[(size_t)n * K + k] = h;
    dl[(size_t)n * K + k] = l;
}

// ---------------- LayerNorm -> single bf16 ----------------
template<bool REMAP, bool F32>
__device__ void ln_body(const void* x, const void* sc, const void* bi,
                        bfu* o, int row0)
{
    const int rg = row0 + blockIdx.x;
    size_t src;
    if (REMAP) {
        int w = rg >> 6, n = rg & 63;
        int b = w >> 8, wi = (w >> 4) & 15, wj = w & 15;
        int ii = wi * 8 + (n >> 3), jj = wj * 8 + (n & 7);
        int si = (ii + SHIFT) & 127, sj = (jj + SHIFT) & 127;
        src = (((size_t)b << 14) + ((size_t)si << 7) + sj) * CC;
    } else {
        src = (size_t)rg * CC;
    }
    const int t = threadIdx.x;
    float v0 = F32 ? ((const float*)x)[src + t]       : b2f(((const bfu*)x)[src + t]);
    float v1 = F32 ? ((const float*)x)[src + t + 64]  : b2f(((const bfu*)x)[src + t + 64]);
    float v2 = F32 ? ((const float*)x)[src + t + 128] : b2f(((const bfu*)x)[src + t + 128]);
    float sum = v0 + v1 + v2;
    float sq  = v0 * v0 + v1 * v1 + v2 * v2;
    #pragma unroll
    for (int off = 32; off > 0; off >>= 1) {
        sum += __shfl_xor(sum, off);
        sq  += __shfl_xor(sq, off);
    }
    float mu  = sum * (1.0f / 192.0f);
    float var = sq * (1.0f / 192.0f) - mu * mu;
    float rs  = rsqrtf(var + 1e-5f);
    size_t dst = (size_t)blockIdx.x * CC;
    const int dual = F32 ? 1 : 0;
    o[dst + t]       = f2b((v0 - mu) * rs * ldgf(dual, sc, t)       + ldgf(dual, bi, t));
    o[dst + t + 64]  = f2b((v1 - mu) * rs * ldgf(dual, sc, t + 64)  + ldgf(dual, bi, t + 64));
    o[dst + t + 128] = f2b((v2 - mu) * rs * ldgf(dual, sc, t + 128) + ldgf(dual, bi, t + 128));
}

template<bool REMAP>
__global__ __launch_bounds__(64) void ln_kernel(
    const int* __restrict__ flag, const void* __restrict__ x,
    const void* __restrict__ sc, const void* __restrict__ bi,
    bfu* __restrict__ o, int row0)
{
    if (*flag) ln_body<REMAP, true>(x, sc, bi, o, row0);
    else       ln_body<REMAP, false>(x, sc, bi, o, row0);
}

// ---------------- MFMA GEMM (counted-vmcnt pipeline, T4) ----------------
// A: single bf16 [M][K] chunk-local. B: split+transposed (BhT,BlT) bf16 [Npad][K].
// acc = A*Bh (+ A*Bl if fp32 mode; bf16 mode Bl==0 -> skipped).
// Tile 128x128, BK=32, 4 waves (2x2), wave tile 64x64 = 4m x 4n of 16x16x32.
// Pipeline: A staged 3 k-steps ahead (4 LDS bufs, covers HBM latency);
// B staged 1 ahead (2 bufs, L2-hot weights). Raw s_barrier + literal
// s_waitcnt vmcnt(N) -- never 0 in steady state. Per-wave issue per iter:
// B(t+1)=4 ops (2 if !dual), A(t+3)=2. Steady in-flight pre-wait =
// {A(t),A(t+1),A(t+2),B(t)} + {B(t+1),A(t+3)} = 16 (12); drain {A(t),B(t)}
// -> vmcnt(10) dual / vmcnt(8) bf16. Tails: nt-3 -> 8/6, nt-2 -> 6/4, nt-1 -> 0.
// Requires nt >= 4 (K >= 128; all launches use K in {192,768}).
// LDS swizzle unchanged (verified: conflicts == 0).
template<int MODE>
__global__ __launch_bounds__(256) void gemm_kernel(
    const int* __restrict__ flag,
    const bfu* __restrict__ A,
    const bfu* __restrict__ BhT, const bfu* __restrict__ BlT,
    const void* __restrict__ bias, const void* __restrict__ res,
    void* __restrict__ out,
    int K, int Nstr, int Nreal, int row0)
{
    const int dual = *flag;
    __shared__ __align__(16) bfu As [4][4096];   // [buf][128 rows * 32 k]
    __shared__ __align__(16) bfu BsH[2][4096];
    __shared__ __align__(16) bfu BsL[2][4096];
    const int t  = threadIdx.x;
    const int m0 = blockIdx.y * 128;
    const int n0 = blockIdx.x * 128;
    const int l  = t & 63, wv = t >> 6;
    const int wm = wv >> 1, wn = wv & 1;          // 2x2 wave grid
    const int fr = l & 15, j = l >> 4;            // fragment row, 16B slot
    const int q4 = l >> 4;

    // staging geometry: wave wv covers rows 32*wv..32*wv+31 (2 issues of 16 rows)
    const int srow = (l >> 2);                    // 0..15 within issue
    const int slot = (l & 3) ^ ((l >> 3) & 3);    // swizzled k-slot (involution)

    const int nt = K >> 5;

    #define STAGE_A(buf, kk)                                                      \
        do {                                                                      \
            _Pragma("unroll")                                                     \
            for (int i = 0; i < 2; i++) {                                         \
                const int r0 = wv * 32 + 16 * i;                                  \
                gload16(A + (size_t)(m0 + r0 + srow) * K + (kk) + slot * 8,       \
                        &As[buf][r0 * 32]);                                       \
            }                                                                     \
        } while (0)
    #define STAGE_BH(buf, kk)                                                     \
        do {                                                                      \
            _Pragma("unroll")                                                     \
            for (int i = 0; i < 2; i++) {                                         \
                const int r0 = wv * 32 + 16 * i;                                  \
                gload16(BhT + (size_t)(n0 + r0 + srow) * K + (kk) + slot * 8,     \
                        &BsH[buf][r0 * 32]);                                      \
            }                                                                     \
        } while (0)
    #define STAGE_BL(buf, kk)                                                     \
        do {                                                                      \
            _Pragma("unroll")                                                     \
            for (int i = 0; i < 2; i++) {                                         \
                const int r0 = wv * 32 + 16 * i;                                  \
                gload16(BlT + (size_t)(n0 + r0 + srow) * K + (kk) + slot * 8,     \
                        &BsL[buf][r0 * 32]);                                      \
            }                                                                     \
        } while (0)

    f32x4 acc[4][4];
    #pragma unroll
    for (int mt = 0; mt < 4; mt++)
        #pragma unroll
        for (int nt2 = 0; nt2 < 4; nt2++)
            acc[mt][nt2] = f32x4{0.f, 0.f, 0.f, 0.f};

    // prologue: B(0); A(0); A(1); A(2)   (issue order matters for vmcnt math)
    STAGE_BH(0, 0);
    if (dual) STAGE_BL(0, 0);
    STAGE_A(0, 0);
    STAGE_A(1, 32);
    STAGE_A(2, 64);

    for (int tt = 0; tt < nt; ++tt) {
        const int ca = tt & 3, cb = tt & 1;
        if (tt + 1 < nt) {
            STAGE_BH(cb ^ 1, (tt + 1) * 32);
            if (dual) STAGE_BL(cb ^ 1, (tt + 1) * 32);
        }
        if (tt + 3 < nt) STAGE_A((tt + 3) & 3, (tt + 3) * 32);

        // counted wait: own A(tt) and B(tt) landed; leave prefetches in flight
        if (tt + 3 < nt) {
            if (dual) asm volatile("s_waitcnt vmcnt(10)" ::: "memory");
            else      asm volatile("s_waitcnt vmcnt(8)"  ::: "memory");
        } else if (tt + 2 < nt) {
            if (dual) asm volatile("s_waitcnt vmcnt(8)"  ::: "memory");
            else      asm volatile("s_waitcnt vmcnt(6)"  ::: "memory");
        } else if (tt + 1 < nt) {
            if (dual) asm volatile("s_waitcnt vmcnt(6)"  ::: "memory");
            else      asm volatile("s_waitcnt vmcnt(4)"  ::: "memory");
        } else {
            asm volatile("s_waitcnt vmcnt(0)" ::: "memory");
        }
        asm volatile("s_barrier" ::: "memory");   // all waves' buf-tt loads landed

        bf16x8 af[4], bh[4];
        #pragma unroll
        for (int mt = 0; mt < 4; mt++) {
            const int row = wm * 64 + mt * 16 + fr;
            const int ph  = j ^ ((row >> 1) & 3);
            af[mt] = *(const bf16x8*)&As[ca][row * 32 + ph * 8];
        }
        #pragma unroll
        for (int nn = 0; nn < 4; nn++) {
            const int row = wn * 64 + nn * 16 + fr;
            const int ph  = j ^ ((row >> 1) & 3);
            bh[nn] = *(const bf16x8*)&BsH[cb][row * 32 + ph * 8];
        }
        #pragma unroll
        for (int mt = 0; mt < 4; mt++)
            #pragma unroll
            for (int nn = 0; nn < 4; nn++)
                acc[mt][nn] = __builtin_amdgcn_mfma_f32_16x16x32_bf16(af[mt], bh[nn], acc[mt][nn], 0, 0, 0);
        if (dual) {
            bf16x8 bl[4];
            #pragma unroll
            for (int nn = 0; nn < 4; nn++) {
                const int row = wn * 64 + nn * 16 + fr;
                const int ph  = j ^ ((row >> 1) & 3);
                bl[nn] = *(const bf16x8*)&BsL[cb][row * 32 + ph * 8];
            }
            #pragma unroll
            for (int mt = 0; mt < 4; mt++)
                #pragma unroll
                for (int nn = 0; nn < 4; nn++)
                    acc[mt][nn] = __builtin_amdgcn_mfma_f32_16x16x32_bf16(af[mt], bl[nn], acc[mt][nn], 0, 0, 0);
        }
        if (tt + 1 < nt)
            asm volatile("s_barrier" ::: "memory");  // all reads done before overwrite
    }
    #undef STAGE_A
    #undef STAGE_BH
    #undef STAGE_BL

    float bia[4];
    #pragma unroll
    for (int nn = 0; nn < 4; nn++) {
        int col = n0 + wn * 64 + nn * 16 + fr;
        bia[nn] = (col < Nreal) ? ldgf(dual, bias, col) : 0.0f;
    }

    #pragma unroll
    for (int mt = 0; mt < 4; mt++) {
        #pragma unroll
        for (int r = 0; r < 4; r++) {
            const int rl = m0 + wm * 64 + mt * 16 + q4 * 4 + r;
            size_t orow;
            if (MODE == 1) {
                int rg = row0 + rl;
                int w = rg >> 6, n = rg & 63;
                int b_ = w >> 8, wi = (w >> 4) & 15, wj = w & 15;
                int ii = wi * 8 + (n >> 3), jj = wj * 8 + (n & 7);
                int fi = (ii + SHIFT) & 127, fj = (jj + SHIFT) & 127;
                orow = ((size_t)b_ << 14) + ((size_t)fi << 7) + fj;
            } else if (MODE == 3) {
                orow = (size_t)(row0 + rl);
            } else {
                orow = (size_t)rl;
            }
            #pragma unroll
            for (int nn = 0; nn < 4; nn++) {
                int col = n0 + wn * 64 + nn * 16 + fr;
                if ((MODE == 1 || MODE == 3) && col >= Nreal) continue;
                size_t o = orow * Nstr + col;
                float v = acc[mt][nn][r] + bia[nn];
                if (MODE == 1 || MODE == 3) {
                    v += ldgf(dual, res, o);
                    stgf(dual, out, o, v);
                } else if (MODE == 2) {
                    v = v * 0.5f * (1.0f + erff(v * 0.70710678118654752f));
                    ((bfu*)out)[o] = f2b(v);
                } else {
                    ((bfu*)out)[o] = f2b(v);
                }
            }
        }
    }
}

// ---------------- Windowed attention (bf16 qkv in, bf16 out) ----------------
__global__ __launch_bounds__(256) void attn_kernel(
    const int* __restrict__ flag, const bfu* __restrict__ qkv,
    const void* __restrict__ rpb, bfu* __restrict__ outp)
{
    const int dual = *flag;
    __shared__ __align__(16) float qT[32][64];
    __shared__ __align__(16) float kT[32][64];
    __shared__ __align__(16) float vsm[64][32];
    __shared__ __align__(16) float S[64][68];
    __shared__ float bias_s[225 * 6];
    const int t = threadIdx.x;
    const int w = blockIdx.x / 6;
    const int h = blockIdx.x % 6;

    if (dual) { for (int i = t; i < 1350; i += 256) bias_s[i] = ((const float*)rpb)[i]; }
    else      { for (int i = t; i < 1350; i += 256) bias_s[i] = b2f(((const bfu*)rpb)[i]); }
    {
        const int n = t >> 2, d0 = (t & 3) * 8;
        size_t base = (size_t)(w * 64 + n) * C3P + h * 32 + d0;
        bf16x8 vq = *(const bf16x8*)&qkv[base];
        bf16x8 vk = *(const bf16x8*)&qkv[base + 192];
        bf16x8 vv = *(const bf16x8*)&qkv[base + 384];
        #pragma unroll
        for (int i = 0; i < 8; i++) {
            qT[d0 + i][n]  = b2f((bfu)vq[i]);
            kT[d0 + i][n]  = b2f((bfu)vk[i]);
            vsm[n][d0 + i] = b2f((bfu)vv[i]);
        }
    }
    __syncthreads();

    {
        const int i0 = (t >> 4) * 4, j0 = (t & 15) * 4;
        float sacc[4][4] = {};
        #pragma unroll
        for (int kk = 0; kk < 32; kk++) {
            float4 q4 = *reinterpret_cast<float4*>(&qT[kk][i0]);
            float4 k4 = *reinterpret_cast<float4*>(&kT[kk][j0]);
            float qa[4] = {q4.x, q4.y, q4.z, q4.w};
            float kb[4] = {k4.x, k4.y, k4.z, k4.w};
            #pragma unroll
            for (int a = 0; a < 4; a++)
                #pragma unroll
                for (int b = 0; b < 4; b++)
                    sacc[a][b] += qa[a] * kb[b];
        }
        #pragma unroll
        for (int a = 0; a < 4; a++) {
            int i = i0 + a;
            #pragma unroll
            for (int b = 0; b < 4; b++) {
                int j = j0 + b;
                int rel = ((i >> 3) - (j >> 3) + 7) * 15 + ((i & 7) - (j & 7) + 7);
                S[i][j] = sacc[a][b] * 0.17677669529663687f + bias_s[rel * 6 + h];
            }
        }
    }
    __syncthreads();

    {
        const int r = t >> 2, q = (t & 3) * 16;
        float mx = -1e30f;
        #pragma unroll
        for (int j = 0; j < 16; j++) mx = fmaxf(mx, S[r][q + j]);
        mx = fmaxf(mx, __shfl_xor(mx, 1));
        mx = fmaxf(mx, __shfl_xor(mx, 2));
        float sm = 0.f;
        #pragma unroll
        for (int j = 0; j < 16; j++) { float e = __expf(S[r][q + j] - mx); S[r][q + j] = e; sm += e; }
        sm += __shfl_xor(sm, 1);
        sm += __shfl_xor(sm, 2);
        float inv = 1.0f / sm;
        #pragma unroll
        for (int j = 0; j < 16; j++) S[r][q + j] *= inv;
    }
    __syncthreads();

    {
        const int oi = (t >> 4) * 4, d0 = (t & 15) * 2;
        float a0 = 0, a1 = 0, a2 = 0, a3 = 0, c0 = 0, c1 = 0, c2 = 0, c3 = 0;
        for (int j = 0; j < 64; j++) {
            float2 vj = *reinterpret_cast<float2*>(&vsm[j][d0]);
            float s0 = S[oi][j], s1 = S[oi + 1][j], s2 = S[oi + 2][j], s3 = S[oi + 3][j];
            a0 += s0 * vj.x; c0 += s0 * vj.y;
            a1 += s1 * vj.x; c1 += s1 * vj.y;
            a2 += s2 * vj.x; c2 += s2 * vj.y;
            a3 += s3 * vj.x; c3 += s3 * vj.y;
        }
        float oa[4] = {a0, a1, a2, a3}, ob[4] = {c0, c1, c2, c3};
        #pragma unroll
        for (int a = 0; a < 4; a++) {
            size_t o = (size_t)(w * 64 + oi + a) * CC + h * 32 + d0;
            unsigned pk = (unsigned)f2b(oa[a]) | ((unsigned)f2b(ob[a]) << 16);
            *(unsigned*)&outp[o] = pk;
        }
    }
}

// ---------------- launch ----------------
extern "C" void kernel_launch(void* const* d_in, const int* in_sizes, int n_in,
                              void* d_out, int out_size, void* d_ws, size_t ws_size,
                              hipStream_t stream)
{
    const void* x      = d_in[0];
    const void* qkv_w  = d_in[1];
    const void* qkv_b  = d_in[2];
    const void* proj_w = d_in[3];
    const void* proj_b = d_in[4];
    const void* rpb    = d_in[5];
    const void* n1s    = d_in[6];
    const void* n1b    = d_in[7];
    const void* n2s    = d_in[8];
    const void* n2b    = d_in[9];
    const void* w1     = d_in[10];
    const void* b1     = d_in[11];
    const void* w2     = d_in[12];
    const void* b2     = d_in[13];

    // per-chunk intermediates: 2048 B/row (phase1: xw 384 + qkvc 1280 + ao 384)
    int nch = 1;
    while (nch < 128 && ((size_t)(MROWS / nch) * 2048 + 1024 + WBYTES) > ws_size) nch *= 2;
    const int R = MROWS / nch;

    int* flag = (int*)d_ws;
    bfu* wb   = (bfu*)((char*)d_ws + 1024);
    // weight areas (bfu offsets): qkv 640x192, proj 256x192, w1 768x192, w2 256x768
    bfu* wqH = wb;           bfu* wqL = wb + 122880;
    bfu* wpH = wb + 245760;  bfu* wpL = wb + 294912;
    bfu* w1H = wb + 344064;  bfu* w1L = wb + 491520;
    bfu* w2H = wb + 638976;  bfu* w2L = wb + 835584;
    bfu* fB  = wb + 1032192;                       // chunk area

    // phase 1 layout (bfu units): xw R*192 | qkvc R*640 | ao R*192
    bfu* xw   = fB;
    bfu* qkvc = fB + (size_t)R * 192;
    bfu* ao   = fB + (size_t)R * 832;
    // phase 2 layout: xn R*192 | hb R*768
    bfu* xn   = fB;
    bfu* hb   = fB + (size_t)R * 192;

    detect_kernel<<<1, 256, 0, stream>>>(x, flag);
    prep_kernel<<<dim3(3, 640),  64, 0, stream>>>(flag, qkv_w,  wqH, wqL, 192, 576);
    prep_kernel<<<dim3(3, 256),  64, 0, stream>>>(flag, proj_w, wpH, wpL, 192, 192);
    prep_kernel<<<dim3(3, 768),  64, 0, stream>>>(flag, w1,     w1H, w1L, 192, 768);
    prep_kernel<<<dim3(12, 256), 64, 0, stream>>>(flag, w2,     w2H, w2L, 768, 192);

    // phase 1: LN1+shift+window -> qkv -> attn -> proj+unshift+residual(x) -> d_out
    for (int c = 0; c < nch; c++) {
        const int row0 = c * R;
        ln_kernel<true><<<R, 64, 0, stream>>>(flag, x, n1s, n1b, xw, row0);
        gemm_kernel<0><<<dim3(5, R / 128), 256, 0, stream>>>(
            flag, xw, wqH, wqL, qkv_b, nullptr, qkvc, 192, C3P, 576, 0);
        attn_kernel<<<(R / 64) * 6, 256, 0, stream>>>(flag, qkvc, rpb, ao);
        gemm_kernel<1><<<dim3(2, R / 128), 256, 0, stream>>>(
            flag, ao, wpH, wpL, proj_b, x, d_out, 192, CC, CC, row0);
    }

    // phase 2: LN2 -> mlp1+gelu -> mlp2+residual ; x2 lives in d_out (global rows)
    for (int c = 0; c < nch; c++) {
        const int row0 = c * R;
        ln_kernel<false><<<R, 64, 0, stream>>>(flag, d_out, n2s, n2b, xn, row0);
        gemm_kernel<2><<<dim3(6, R / 128), 256, 0, stream>>>(
            flag, xn, w1H, w1L, b1, nullptr, hb, 192, CM, CM, 0);
        gemm_kernel<3><<<dim3(2, R / 128), 256, 0, stream>>>(
            flag, hb, w2H, w2L, b2, d_out, d_out, 768, CC, CC, row0);
    }
}

// Round 7
// 1030.866 us; speedup vs baseline: 1.9824x; 1.0210x over previous
//
#include <hip/hip_runtime.h>
#include <math.h>

typedef unsigned short bfu;
typedef __attribute__((ext_vector_type(4))) float  f32x4;
typedef __attribute__((ext_vector_type(8))) short  bf16x8;

// ---------- scalar bf16 helpers ----------
__device__ __forceinline__ float b2f(bfu v) { return __uint_as_float((unsigned)v << 16); }
__device__ __forceinline__ bfu f2b(float f) {
    unsigned u = __float_as_uint(f);
    u += 0x7fffu + ((u >> 16) & 1u);   // RNE
    return (bfu)(u >> 16);
}
__device__ __forceinline__ void splitf(float x, bfu& h, bfu& l) {
    h = f2b(x);
    l = f2b(x - b2f(h));
}
// runtime dtype-dual load/store (dual=1 -> fp32, dual=0 -> bf16)
__device__ __forceinline__ float ldgf(int dual, const void* p, size_t i) {
    return dual ? ((const float*)p)[i] : b2f(((const bfu*)p)[i]);
}
__device__ __forceinline__ void stgf(int dual, void* p, size_t i, float v) {
    if (dual) ((float*)p)[i] = v;
    else      ((bfu*)p)[i] = f2b(v);
}

// Problem constants
#define CC    192
#define C3P   640      // qkv columns padded 576 -> 640
#define CM    768
#define MROWS 131072   // 8*128*128
#define SHIFT 4
#define WBYTES 2064384 // split+transposed weight area (padded N)

// ---------------- dtype probe ----------------
__global__ void detect_kernel(const void* x, int* flag) {
    __shared__ int bad;
    if (threadIdx.x == 0) bad = 0;
    __syncthreads();
    int local = 0;
    for (int i = 0; i < 16; i++) {
        float v = b2f(((const bfu*)x)[threadIdx.x + i * 256]);
        if (!(fabsf(v) < 1000.0f)) local = 1;
    }
    if (local) atomicOr(&bad, 1);
    __syncthreads();
    if (threadIdx.x == 0) *flag = bad;          // 1 -> fp32, 0 -> bf16
}

// ---------------- weight prep: split + transpose (+ zero pad rows) ----------------
__global__ __launch_bounds__(64) void prep_kernel(
    const int* __restrict__ flag, const void* __restrict__ w,
    bfu* __restrict__ dh, bfu* __restrict__ dl, int K, int Nreal)
{
    const int k = blockIdx.x * 64 + threadIdx.x;
    const int n = blockIdx.y;
    float v = 0.0f;
    if (n < Nreal)
        v = (*flag) ? ((const float*)w)[(size_t)k * Nreal + n]
                    : b2f(((const bfu*)w)[(size_t)k * Nreal + n]);
    bfu h, l;
    splitf(v, h, l);
    dh[(size_t)n * K + k] = h;
    dl[(size_t)n * K + k] = l;
}

// ---------------- LayerNorm -> single bf16 ----------------
template<bool REMAP, bool F32>
__device__ void ln_body(const void* x, const void* sc, const void* bi,
                        bfu* o, int row0)
{
    const int rg = row0 + blockIdx.x;
    size_t src;
    if (REMAP) {
        int w = rg >> 6, n = rg & 63;
        int b = w >> 8, wi = (w >> 4) & 15, wj = w & 15;
        int ii = wi * 8 + (n >> 3), jj = wj * 8 + (n & 7);
        int si = (ii + SHIFT) & 127, sj = (jj + SHIFT) & 127;
        src = (((size_t)b << 14) + ((size_t)si << 7) + sj) * CC;
    } else {
        src = (size_t)rg * CC;
    }
    const int t = threadIdx.x;
    float v0 = F32 ? ((const float*)x)[src + t]       : b2f(((const bfu*)x)[src + t]);
    float v1 = F32 ? ((const float*)x)[src + t + 64]  : b2f(((const bfu*)x)[src + t + 64]);
    float v2 = F32 ? ((const float*)x)[src + t + 128] : b2f(((const bfu*)x)[src + t + 128]);
    float sum = v0 + v1 + v2;
    float sq  = v0 * v0 + v1 * v1 + v2 * v2;
    #pragma unroll
    for (int off = 32; off > 0; off >>= 1) {
        sum += __shfl_xor(sum, off);
        sq  += __shfl_xor(sq, off);
    }
    float mu  = sum * (1.0f / 192.0f);
    float var = sq * (1.0f / 192.0f) - mu * mu;
    float rs  = rsqrtf(var + 1e-5f);
    size_t dst = (size_t)blockIdx.x * CC;
    const int dual = F32 ? 1 : 0;
    o[dst + t]       = f2b((v0 - mu) * rs * ldgf(dual, sc, t)       + ldgf(dual, bi, t));
    o[dst + t + 64]  = f2b((v1 - mu) * rs * ldgf(dual, sc, t + 64)  + ldgf(dual, bi, t + 64));
    o[dst + t + 128] = f2b((v2 - mu) * rs * ldgf(dual, sc, t + 128) + ldgf(dual, bi, t + 128));
}

template<bool REMAP>
__global__ __launch_bounds__(64) void ln_kernel(
    const int* __restrict__ flag, const void* __restrict__ x,
    const void* __restrict__ sc, const void* __restrict__ bi,
    bfu* __restrict__ o, int row0)
{
    if (*flag) ln_body<REMAP, true>(x, sc, bi, o, row0);
    else       ln_body<REMAP, false>(x, sc, bi, o, row0);
}

// ---------------- MFMA GEMM (reg-staged, single-buffer 24KB LDS, T14) ----------------
// A: single bf16 [M][K] chunk-local. B: split+transposed (BhT,BlT) bf16 [Npad][K].
// acc = A*Bh (+ A*Bl if fp32 mode; bf16 mode Bl==0 -> skipped).
// Tile 128x128, BK=32, 4 waves (2x2), wave tile 64x64 = 4m x 4n of 16x16x32.
// Loop (round-2 proven): sync1 -> ds_write regs(t) -> sync2 -> issue
// global loads(t+1) to regs -> ds_read + MFMA(t).  Loads' HBM latency hides
// under the read+MFMA phase; vmcnt absorbed at next iter's ds_write.
// LDS swizzle (verified 0-conflict): 16B slot phys = logical ^ ((row>>1)&3),
// applied on BOTH ds_write and ds_read (reg-staging allows write-side swz).
template<int MODE>
__global__ __launch_bounds__(256) void gemm_kernel(
    const int* __restrict__ flag,
    const bfu* __restrict__ A,
    const bfu* __restrict__ BhT, const bfu* __restrict__ BlT,
    const void* __restrict__ bias, const void* __restrict__ res,
    void* __restrict__ out,
    int K, int Nstr, int Nreal, int row0)
{
    const int dual = *flag;
    __shared__ __align__(16) bfu As [4096];   // 128 rows * 32 k (8 KB)
    __shared__ __align__(16) bfu BsH[4096];
    __shared__ __align__(16) bfu BsL[4096];
    const int t  = threadIdx.x;
    const int m0 = blockIdx.x * 128;          // m-fastest grid (round-2 orientation)
    const int n0 = blockIdx.y * 128;
    const int l  = t & 63, wv = t >> 6;
    const int wm = wv >> 1, wn = wv & 1;      // 2x2 wave grid
    const int fr = l & 15, j = l >> 4;        // fragment row, logical 16B slot
    const int q4 = l >> 4;

    // staging geometry: lane t covers row t>>1, 32B at k-slot pair (t&1)*2
    const int srow = t >> 1;                  // 0..127
    const int s0   = (t & 1) * 2;             // logical slot of first 16B
    const int sw   = (srow >> 1) & 3;         // swizzle term for this row
    const int d0   = srow * 32 + ((s0    ) ^ sw) * 8;   // LDS bfu offsets
    const int d1   = srow * 32 + ((s0 + 1) ^ sw) * 8;

    const bfu* gA = A   + (size_t)(m0 + srow) * K + s0 * 8;
    const bfu* gH = BhT + (size_t)(n0 + srow) * K + s0 * 8;
    const bfu* gL = BlT + (size_t)(n0 + srow) * K + s0 * 8;

    f32x4 acc[4][4];
    #pragma unroll
    for (int mt = 0; mt < 4; mt++)
        #pragma unroll
        for (int nn = 0; nn < 4; nn++)
            acc[mt][nn] = f32x4{0.f, 0.f, 0.f, 0.f};

    // prologue: load tile 0 into regs (64B/row, perfectly coalesced)
    f32x4 ra0 = *(const f32x4*)(gA);
    f32x4 ra1 = *(const f32x4*)(gA + 8);
    f32x4 rh0 = *(const f32x4*)(gH);
    f32x4 rh1 = *(const f32x4*)(gH + 8);
    f32x4 rl0 = f32x4{0.f, 0.f, 0.f, 0.f}, rl1 = rl0;
    if (dual) { rl0 = *(const f32x4*)(gL); rl1 = *(const f32x4*)(gL + 8); }

    for (int k0 = 0; k0 < K; k0 += 32) {
        __syncthreads();                       // readers of previous tile done
        *(f32x4*)&As [d0] = ra0;  *(f32x4*)&As [d1] = ra1;
        *(f32x4*)&BsH[d0] = rh0;  *(f32x4*)&BsH[d1] = rh1;
        if (dual) { *(f32x4*)&BsL[d0] = rl0;  *(f32x4*)&BsL[d1] = rl1; }
        __syncthreads();                       // tile t visible to all

        if (k0 + 32 < K) {                     // issue t+1 loads; hide under MFMA
            ra0 = *(const f32x4*)(gA + k0 + 32);
            ra1 = *(const f32x4*)(gA + k0 + 40);
            rh0 = *(const f32x4*)(gH + k0 + 32);
            rh1 = *(const f32x4*)(gH + k0 + 40);
            if (dual) {
                rl0 = *(const f32x4*)(gL + k0 + 32);
                rl1 = *(const f32x4*)(gL + k0 + 40);
            }
        }

        bf16x8 af[4], bh[4];
        #pragma unroll
        for (int mt = 0; mt < 4; mt++) {
            const int row = wm * 64 + mt * 16 + fr;
            const int ph  = j ^ ((row >> 1) & 3);
            af[mt] = *(const bf16x8*)&As[row * 32 + ph * 8];
        }
        #pragma unroll
        for (int nn = 0; nn < 4; nn++) {
            const int row = wn * 64 + nn * 16 + fr;
            const int ph  = j ^ ((row >> 1) & 3);
            bh[nn] = *(const bf16x8*)&BsH[row * 32 + ph * 8];
        }
        #pragma unroll
        for (int mt = 0; mt < 4; mt++)
            #pragma unroll
            for (int nn = 0; nn < 4; nn++)
                acc[mt][nn] = __builtin_amdgcn_mfma_f32_16x16x32_bf16(af[mt], bh[nn], acc[mt][nn], 0, 0, 0);
        if (dual) {
            bf16x8 bl[4];
            #pragma unroll
            for (int nn = 0; nn < 4; nn++) {
                const int row = wn * 64 + nn * 16 + fr;
                const int ph  = j ^ ((row >> 1) & 3);
                bl[nn] = *(const bf16x8*)&BsL[row * 32 + ph * 8];
            }
            #pragma unroll
            for (int mt = 0; mt < 4; mt++)
                #pragma unroll
                for (int nn = 0; nn < 4; nn++)
                    acc[mt][nn] = __builtin_amdgcn_mfma_f32_16x16x32_bf16(af[mt], bl[nn], acc[mt][nn], 0, 0, 0);
        }
    }

    float bia[4];
    #pragma unroll
    for (int nn = 0; nn < 4; nn++) {
        int col = n0 + wn * 64 + nn * 16 + fr;
        bia[nn] = (col < Nreal) ? ldgf(dual, bias, col) : 0.0f;
    }

    #pragma unroll
    for (int mt = 0; mt < 4; mt++) {
        #pragma unroll
        for (int r = 0; r < 4; r++) {
            const int rl = m0 + wm * 64 + mt * 16 + q4 * 4 + r;
            size_t orow;
            if (MODE == 1) {
                int rg = row0 + rl;
                int w = rg >> 6, n = rg & 63;
                int b_ = w >> 8, wi = (w >> 4) & 15, wj = w & 15;
                int ii = wi * 8 + (n >> 3), jj = wj * 8 + (n & 7);
                int fi = (ii + SHIFT) & 127, fj = (jj + SHIFT) & 127;
                orow = ((size_t)b_ << 14) + ((size_t)fi << 7) + fj;
            } else if (MODE == 3) {
                orow = (size_t)(row0 + rl);
            } else {
                orow = (size_t)rl;
            }
            #pragma unroll
            for (int nn = 0; nn < 4; nn++) {
                int col = n0 + wn * 64 + nn * 16 + fr;
                if ((MODE == 1 || MODE == 3) && col >= Nreal) continue;
                size_t o = orow * Nstr + col;
                float v = acc[mt][nn][r] + bia[nn];
                if (MODE == 1 || MODE == 3) {
                    v += ldgf(dual, res, o);
                    stgf(dual, out, o, v);
                } else if (MODE == 2) {
                    v = v * 0.5f * (1.0f + erff(v * 0.70710678118654752f));
                    ((bfu*)out)[o] = f2b(v);
                } else {
                    ((bfu*)out)[o] = f2b(v);
                }
            }
        }
    }
}

// ---------------- Windowed attention (bf16 qkv in, bf16 out) ----------------
__global__ __launch_bounds__(256) void attn_kernel(
    const int* __restrict__ flag, const bfu* __restrict__ qkv,
    const void* __restrict__ rpb, bfu* __restrict__ outp)
{
    const int dual = *flag;
    __shared__ __align__(16) float qT[32][64];
    __shared__ __align__(16) float kT[32][64];
    __shared__ __align__(16) float vsm[64][32];
    __shared__ __align__(16) float S[64][68];
    __shared__ float bias_s[225 * 6];
    const int t = threadIdx.x;
    const int w = blockIdx.x / 6;
    const int h = blockIdx.x % 6;

    if (dual) { for (int i = t; i < 1350; i += 256) bias_s[i] = ((const float*)rpb)[i]; }
    else      { for (int i = t; i < 1350; i += 256) bias_s[i] = b2f(((const bfu*)rpb)[i]); }
    {
        const int n = t >> 2, d0 = (t & 3) * 8;
        size_t base = (size_t)(w * 64 + n) * C3P + h * 32 + d0;
        bf16x8 vq = *(const bf16x8*)&qkv[base];
        bf16x8 vk = *(const bf16x8*)&qkv[base + 192];
        bf16x8 vv = *(const bf16x8*)&qkv[base + 384];
        #pragma unroll
        for (int i = 0; i < 8; i++) {
            qT[d0 + i][n]  = b2f((bfu)vq[i]);
            kT[d0 + i][n]  = b2f((bfu)vk[i]);
            vsm[n][d0 + i] = b2f((bfu)vv[i]);
        }
    }
    __syncthreads();

    {
        const int i0 = (t >> 4) * 4, j0 = (t & 15) * 4;
        float sacc[4][4] = {};
        #pragma unroll
        for (int kk = 0; kk < 32; kk++) {
            float4 q4 = *reinterpret_cast<float4*>(&qT[kk][i0]);
            float4 k4 = *reinterpret_cast<float4*>(&kT[kk][j0]);
            float qa[4] = {q4.x, q4.y, q4.z, q4.w};
            float kb[4] = {k4.x, k4.y, k4.z, k4.w};
            #pragma unroll
            for (int a = 0; a < 4; a++)
                #pragma unroll
                for (int b = 0; b < 4; b++)
                    sacc[a][b] += qa[a] * kb[b];
        }
        #pragma unroll
        for (int a = 0; a < 4; a++) {
            int i = i0 + a;
            #pragma unroll
            for (int b = 0; b < 4; b++) {
                int j = j0 + b;
                int rel = ((i >> 3) - (j >> 3) + 7) * 15 + ((i & 7) - (j & 7) + 7);
                S[i][j] = sacc[a][b] * 0.17677669529663687f + bias_s[rel * 6 + h];
            }
        }
    }
    __syncthreads();

    {
        const int r = t >> 2, q = (t & 3) * 16;
        float mx = -1e30f;
        #pragma unroll
        for (int j = 0; j < 16; j++) mx = fmaxf(mx, S[r][q + j]);
        mx = fmaxf(mx, __shfl_xor(mx, 1));
        mx = fmaxf(mx, __shfl_xor(mx, 2));
        float sm = 0.f;
        #pragma unroll
        for (int j = 0; j < 16; j++) { float e = __expf(S[r][q + j] - mx); S[r][q + j] = e; sm += e; }
        sm += __shfl_xor(sm, 1);
        sm += __shfl_xor(sm, 2);
        float inv = 1.0f / sm;
        #pragma unroll
        for (int j = 0; j < 16; j++) S[r][q + j] *= inv;
    }
    __syncthreads();

    {
        const int oi = (t >> 4) * 4, d0 = (t & 15) * 2;
        float a0 = 0, a1 = 0, a2 = 0, a3 = 0, c0 = 0, c1 = 0, c2 = 0, c3 = 0;
        for (int j = 0; j < 64; j++) {
            float2 vj = *reinterpret_cast<float2*>(&vsm[j][d0]);
            float s0 = S[oi][j], s1 = S[oi + 1][j], s2 = S[oi + 2][j], s3 = S[oi + 3][j];
            a0 += s0 * vj.x; c0 += s0 * vj.y;
            a1 += s1 * vj.x; c1 += s1 * vj.y;
            a2 += s2 * vj.x; c2 += s2 * vj.y;
            a3 += s3 * vj.x; c3 += s3 * vj.y;
        }
        float oa[4] = {a0, a1, a2, a3}, ob[4] = {c0, c1, c2, c3};
        #pragma unroll
        for (int a = 0; a < 4; a++) {
            size_t o = (size_t)(w * 64 + oi + a) * CC + h * 32 + d0;
            unsigned pk = (unsigned)f2b(oa[a]) | ((unsigned)f2b(ob[a]) << 16);
            *(unsigned*)&outp[o] = pk;
        }
    }
}

// ---------------- launch ----------------
extern "C" void kernel_launch(void* const* d_in, const int* in_sizes, int n_in,
                              void* d_out, int out_size, void* d_ws, size_t ws_size,
                              hipStream_t stream)
{
    const void* x      = d_in[0];
    const void* qkv_w  = d_in[1];
    const void* qkv_b  = d_in[2];
    const void* proj_w = d_in[3];
    const void* proj_b = d_in[4];
    const void* rpb    = d_in[5];
    const void* n1s    = d_in[6];
    const void* n1b    = d_in[7];
    const void* n2s    = d_in[8];
    const void* n2b    = d_in[9];
    const void* w1     = d_in[10];
    const void* b1     = d_in[11];
    const void* w2     = d_in[12];
    const void* b2     = d_in[13];

    // per-chunk intermediates: 2048 B/row (phase1: xw 384 + qkvc 1280 + ao 384)
    int nch = 1;
    while (nch < 128 && ((size_t)(MROWS / nch) * 2048 + 1024 + WBYTES) > ws_size) nch *= 2;
    const int R = MROWS / nch;

    int* flag = (int*)d_ws;
    bfu* wb   = (bfu*)((char*)d_ws + 1024);
    // weight areas (bfu offsets): qkv 640x192, proj 256x192, w1 768x192, w2 256x768
    bfu* wqH = wb;           bfu* wqL = wb + 122880;
    bfu* wpH = wb + 245760;  bfu* wpL = wb + 294912;
    bfu* w1H = wb + 344064;  bfu* w1L = wb + 491520;
    bfu* w2H = wb + 638976;  bfu* w2L = wb + 835584;
    bfu* fB  = wb + 1032192;                       // chunk area

    // phase 1 layout (bfu units): xw R*192 | qkvc R*640 | ao R*192
    bfu* xw   = fB;
    bfu* qkvc = fB + (size_t)R * 192;
    bfu* ao   = fB + (size_t)R * 832;
    // phase 2 layout: xn R*192 | hb R*768
    bfu* xn   = fB;
    bfu* hb   = fB + (size_t)R * 192;

    detect_kernel<<<1, 256, 0, stream>>>(x, flag);
    prep_kernel<<<dim3(3, 640),  64, 0, stream>>>(flag, qkv_w,  wqH, wqL, 192, 576);
    prep_kernel<<<dim3(3, 256),  64, 0, stream>>>(flag, proj_w, wpH, wpL, 192, 192);
    prep_kernel<<<dim3(3, 768),  64, 0, stream>>>(flag, w1,     w1H, w1L, 192, 768);
    prep_kernel<<<dim3(12, 256), 64, 0, stream>>>(flag, w2,     w2H, w2L, 768, 192);

    // phase 1: LN1+shift+window -> qkv -> attn -> proj+unshift+residual(x) -> d_out
    for (int c = 0; c < nch; c++) {
        const int row0 = c * R;
        ln_kernel<true><<<R, 64, 0, stream>>>(flag, x, n1s, n1b, xw, row0);
        gemm_kernel<0><<<dim3(R / 128, 5), 256, 0, stream>>>(
            flag, xw, wqH, wqL, qkv_b, nullptr, qkvc, 192, C3P, 576, 0);
        attn_kernel<<<(R / 64) * 6, 256, 0, stream>>>(flag, qkvc, rpb, ao);
        gemm_kernel<1><<<dim3(R / 128, 2), 256, 0, stream>>>(
            flag, ao, wpH, wpL, proj_b, x, d_out, 192, CC, CC, row0);
    }

    // phase 2: LN2 -> mlp1+gelu -> mlp2+residual ; x2 lives in d_out (global rows)
    for (int c = 0; c < nch; c++) {
        const int row0 = c * R;
        ln_kernel<false><<<R, 64, 0, stream>>>(flag, d_out, n2s, n2b, xn, row0);
        gemm_kernel<2><<<dim3(R / 128, 6), 256, 0, stream>>>(
            flag, xn, w1H, w1L, b1, nullptr, hb, 192, CM, CM, 0);
        gemm_kernel<3><<<dim3(R / 128, 2), 256, 0, stream>>>(
            flag, hb, w2H, w2L, b2, d_out, d_out, 768, CC, CC, row0);
    }
}

// Round 9
// 862.979 us; speedup vs baseline: 2.3681x; 1.1945x over previous
//
#include <hip/hip_runtime.h>
#include <math.h>

typedef unsigned short bfu;
typedef __attribute__((ext_vector_type(4))) float  f32x4;
typedef __attribute__((ext_vector_type(8))) short  bf16x8;

// ---------- scalar bf16 helpers ----------
__device__ __forceinline__ float b2f(bfu v) { return __uint_as_float((unsigned)v << 16); }
__device__ __forceinline__ bfu f2b(float f) {
    unsigned u = __float_as_uint(f);
    u += 0x7fffu + ((u >> 16) & 1u);   // RNE
    return (bfu)(u >> 16);
}
__device__ __forceinline__ void splitf(float x, bfu& h, bfu& l) {
    h = f2b(x);
    l = f2b(x - b2f(h));
}
// runtime dtype-dual load/store (dual=1 -> fp32, dual=0 -> bf16)
__device__ __forceinline__ float ldgf(int dual, const void* p, size_t i) {
    return dual ? ((const float*)p)[i] : b2f(((const bfu*)p)[i]);
}
__device__ __forceinline__ void stgf(int dual, void* p, size_t i, float v) {
    if (dual) ((float*)p)[i] = v;
    else      ((bfu*)p)[i] = f2b(v);
}

// Problem constants
#define CC    192
#define C3    576
#define CM    768
#define MROWS 131072   // 8*128*128
#define SHIFT 4
#define WBYTES 2064384 // split+transposed weight area

// ---------------- dtype probe ----------------
__global__ void detect_kernel(const void* x, int* flag) {
    __shared__ int bad;
    if (threadIdx.x == 0) bad = 0;
    __syncthreads();
    int local = 0;
    for (int i = 0; i < 16; i++) {
        float v = b2f(((const bfu*)x)[threadIdx.x + i * 256]);
        if (!(fabsf(v) < 1000.0f)) local = 1;
    }
    if (local) atomicOr(&bad, 1);
    __syncthreads();
    if (threadIdx.x == 0) *flag = bad;          // 1 -> fp32, 0 -> bf16
}

// ---------------- weight prep: split + transpose ----------------
__global__ __launch_bounds__(64) void prep_kernel(
    const int* __restrict__ flag, const void* __restrict__ w,
    bfu* __restrict__ dh, bfu* __restrict__ dl, int K, int Nreal)
{
    const int k = blockIdx.x * 64 + threadIdx.x;
    const int n = blockIdx.y;
    float v = 0.0f;
    if (n < Nreal)
        v = (*flag) ? ((const float*)w)[(size_t)k * Nreal + n]
                    : b2f(((const bfu*)w)[(size_t)k * Nreal + n]);
    bfu h, l;
    splitf(v, h, l);
    dh[(size_t)n * K + k] = h;
    dl[(size_t)n * K + k] = l;
}

// ---------------- LayerNorm -> single bf16 ----------------
template<bool REMAP, bool F32>
__device__ void ln_body(const void* x, const void* sc, const void* bi,
                        bfu* o, int row0)
{
    const int rg = row0 + blockIdx.x;
    size_t src;
    if (REMAP) {
        int w = rg >> 6, n = rg & 63;
        int b = w >> 8, wi = (w >> 4) & 15, wj = w & 15;
        int ii = wi * 8 + (n >> 3), jj = wj * 8 + (n & 7);
        int si = (ii + SHIFT) & 127, sj = (jj + SHIFT) & 127;
        src = (((size_t)b << 14) + ((size_t)si << 7) + sj) * CC;
    } else {
        src = (size_t)rg * CC;
    }
    const int t = threadIdx.x;
    float v0 = F32 ? ((const float*)x)[src + t]       : b2f(((const bfu*)x)[src + t]);
    float v1 = F32 ? ((const float*)x)[src + t + 64]  : b2f(((const bfu*)x)[src + t + 64]);
    float v2 = F32 ? ((const float*)x)[src + t + 128] : b2f(((const bfu*)x)[src + t + 128]);
    float sum = v0 + v1 + v2;
    float sq  = v0 * v0 + v1 * v1 + v2 * v2;
    #pragma unroll
    for (int off = 32; off > 0; off >>= 1) {
        sum += __shfl_xor(sum, off);
        sq  += __shfl_xor(sq, off);
    }
    float mu  = sum * (1.0f / 192.0f);
    float var = sq * (1.0f / 192.0f) - mu * mu;
    float rs  = rsqrtf(var + 1e-5f);
    size_t dst = (size_t)blockIdx.x * CC;
    const int dual = F32 ? 1 : 0;
    o[dst + t]       = f2b((v0 - mu) * rs * ldgf(dual, sc, t)       + ldgf(dual, bi, t));
    o[dst + t + 64]  = f2b((v1 - mu) * rs * ldgf(dual, sc, t + 64)  + ldgf(dual, bi, t + 64));
    o[dst + t + 128] = f2b((v2 - mu) * rs * ldgf(dual, sc, t + 128) + ldgf(dual, bi, t + 128));
}

template<bool REMAP>
__global__ __launch_bounds__(64) void ln_kernel(
    const int* __restrict__ flag, const void* __restrict__ x,
    const void* __restrict__ sc, const void* __restrict__ bi,
    bfu* __restrict__ o, int row0)
{
    if (*flag) ln_body<REMAP, true>(x, sc, bi, o, row0);
    else       ln_body<REMAP, false>(x, sc, bi, o, row0);
}

// ---------------- MFMA GEMM (128x64 tile = measured-best shape) ----------------
// A: single bf16 [M][K] chunk-local. B: split+transposed (BhT,BlT) bf16 [N][K].
// acc = A*Bh (+ A*Bl if fp32 mode; bf16 mode Bl==0 -> skipped).
// Tile 128x64, BK=32, 4 waves (2x2), wave tile 64x32 = 4m x 2n of 16x16x32.
// 16 KB LDS + ~90 VGPR -> 5+ resident blocks/CU (the round-2 structure that
// measured 791 TF executed, vs 404 TF for every 128x128 variant).
// Grid n-fastest: A m-panel streamed once, B panels (<=590 KB) L2-hot.
// LDS swizzle (verified 0-conflict): 16B slot phys = logical ^ ((row>>1)&3).
template<int MODE>
__global__ __launch_bounds__(256) void gemm_kernel(
    const int* __restrict__ flag,
    const bfu* __restrict__ A,
    const bfu* __restrict__ BhT, const bfu* __restrict__ BlT,
    const void* __restrict__ bias, const void* __restrict__ res,
    void* __restrict__ out,
    int K, int Nstr, int Nreal, int row0)
{
    const int dual = *flag;
    __shared__ __align__(16) bfu As [4096];   // 128 rows * 32 k (8 KB)
    __shared__ __align__(16) bfu BsH[2048];   // 64 rows * 32 k (4 KB)
    __shared__ __align__(16) bfu BsL[2048];
    const int t  = threadIdx.x;
    const int n0 = blockIdx.x * 64;           // n-fastest
    const int m0 = blockIdx.y * 128;
    const int l  = t & 63, wv = t >> 6;
    const int wm = wv >> 1, wn = wv & 1;      // 2x2 wave grid: 64 rows x 32 cols
    const int fr = l & 15, j = l >> 4;        // fragment row, logical 16B slot
    const int q4 = l >> 4;

    // A staging: lane t covers row t>>1, 2x16B at logical slots (t&1)*2, +1
    const int arow = t >> 1, as0 = (t & 1) * 2;
    const int asw  = (arow >> 1) & 3;
    const int ad0  = arow * 32 + ((as0    ) ^ asw) * 8;
    const int ad1  = arow * 32 + ((as0 + 1) ^ asw) * 8;
    // B staging: lane t covers row t>>2, 1x16B at logical slot t&3
    const int brow = t >> 2, bs0 = t & 3;
    const int bd0  = brow * 32 + (bs0 ^ ((brow >> 1) & 3)) * 8;

    const bfu* gA = A   + (size_t)(m0 + arow) * K + as0 * 8;
    const bfu* gH = BhT + (size_t)(n0 + brow) * K + bs0 * 8;
    const bfu* gL = BlT + (size_t)(n0 + brow) * K + bs0 * 8;

    f32x4 acc[4][2];
    #pragma unroll
    for (int mt = 0; mt < 4; mt++)
        #pragma unroll
        for (int nn = 0; nn < 2; nn++)
            acc[mt][nn] = f32x4{0.f, 0.f, 0.f, 0.f};

    // prologue: tile 0 into regs (coalesced 64B/row A, 64B/row B)
    f32x4 ra0 = *(const f32x4*)(gA);
    f32x4 ra1 = *(const f32x4*)(gA + 8);
    f32x4 rh0 = *(const f32x4*)(gH);
    f32x4 rl0 = f32x4{0.f, 0.f, 0.f, 0.f};
    if (dual) rl0 = *(const f32x4*)(gL);

    for (int k0 = 0; k0 < K; k0 += 32) {
        __syncthreads();                       // readers of previous tile done
        *(f32x4*)&As [ad0] = ra0;  *(f32x4*)&As [ad1] = ra1;
        *(f32x4*)&BsH[bd0] = rh0;
        if (dual) *(f32x4*)&BsL[bd0] = rl0;
        __syncthreads();                       // tile visible to all

        if (k0 + 32 < K) {                     // issue t+1 loads; hide under MFMA
            ra0 = *(const f32x4*)(gA + k0 + 32);
            ra1 = *(const f32x4*)(gA + k0 + 40);
            rh0 = *(const f32x4*)(gH + k0 + 32);
            if (dual) rl0 = *(const f32x4*)(gL + k0 + 32);
        }

        bf16x8 af[4], bh[2];
        #pragma unroll
        for (int mt = 0; mt < 4; mt++) {
            const int row = wm * 64 + mt * 16 + fr;
            const int ph  = j ^ ((row >> 1) & 3);
            af[mt] = *(const bf16x8*)&As[row * 32 + ph * 8];
        }
        #pragma unroll
        for (int nn = 0; nn < 2; nn++) {
            const int row = wn * 32 + nn * 16 + fr;
            const int ph  = j ^ ((row >> 1) & 3);
            bh[nn] = *(const bf16x8*)&BsH[row * 32 + ph * 8];
        }
        #pragma unroll
        for (int mt = 0; mt < 4; mt++)
            #pragma unroll
            for (int nn = 0; nn < 2; nn++)
                acc[mt][nn] = __builtin_amdgcn_mfma_f32_16x16x32_bf16(af[mt], bh[nn], acc[mt][nn], 0, 0, 0);
        if (dual) {
            bf16x8 bl[2];
            #pragma unroll
            for (int nn = 0; nn < 2; nn++) {
                const int row = wn * 32 + nn * 16 + fr;
                const int ph  = j ^ ((row >> 1) & 3);
                bl[nn] = *(const bf16x8*)&BsL[row * 32 + ph * 8];
            }
            #pragma unroll
            for (int mt = 0; mt < 4; mt++)
                #pragma unroll
                for (int nn = 0; nn < 2; nn++)
                    acc[mt][nn] = __builtin_amdgcn_mfma_f32_16x16x32_bf16(af[mt], bl[nn], acc[mt][nn], 0, 0, 0);
        }
    }

    float bia[2];
    #pragma unroll
    for (int nn = 0; nn < 2; nn++) {
        int col = n0 + wn * 32 + nn * 16 + fr;
        bia[nn] = (col < Nreal) ? ldgf(dual, bias, col) : 0.0f;
    }

    #pragma unroll
    for (int mt = 0; mt < 4; mt++) {
        #pragma unroll
        for (int r = 0; r < 4; r++) {
            const int rl = m0 + wm * 64 + mt * 16 + q4 * 4 + r;
            size_t orow;
            if (MODE == 1) {
                int rg = row0 + rl;
                int w = rg >> 6, n = rg & 63;
                int b_ = w >> 8, wi = (w >> 4) & 15, wj = w & 15;
                int ii = wi * 8 + (n >> 3), jj = wj * 8 + (n & 7);
                int fi = (ii + SHIFT) & 127, fj = (jj + SHIFT) & 127;
                orow = ((size_t)b_ << 14) + ((size_t)fi << 7) + fj;
            } else if (MODE == 3) {
                orow = (size_t)(row0 + rl);
            } else {
                orow = (size_t)rl;
            }
            #pragma unroll
            for (int nn = 0; nn < 2; nn++) {
                int col = n0 + wn * 32 + nn * 16 + fr;
                if ((MODE == 1 || MODE == 3) && col >= Nreal) continue;
                size_t o = orow * Nstr + col;
                float v = acc[mt][nn][r] + bia[nn];
                if (MODE == 1 || MODE == 3) {
                    v += ldgf(dual, res, o);
                    stgf(dual, out, o, v);
                } else if (MODE == 2) {
                    v = v * 0.5f * (1.0f + erff(v * 0.70710678118654752f));
                    ((bfu*)out)[o] = f2b(v);
                } else {
                    ((bfu*)out)[o] = f2b(v);
                }
            }
        }
    }
}

// ---------------- Windowed attention (bf16 qkv in, bf16 out) ----------------
__global__ __launch_bounds__(256) void attn_kernel(
    const int* __restrict__ flag, const bfu* __restrict__ qkv,
    const void* __restrict__ rpb, bfu* __restrict__ outp)
{
    const int dual = *flag;
    __shared__ __align__(16) float qT[32][64];
    __shared__ __align__(16) float kT[32][64];
    __shared__ __align__(16) float vsm[64][32];
    __shared__ __align__(16) float S[64][68];
    __shared__ float bias_s[225 * 6];
    const int t = threadIdx.x;
    const int w = blockIdx.x / 6;
    const int h = blockIdx.x % 6;

    if (dual) { for (int i = t; i < 1350; i += 256) bias_s[i] = ((const float*)rpb)[i]; }
    else      { for (int i = t; i < 1350; i += 256) bias_s[i] = b2f(((const bfu*)rpb)[i]); }
    {
        const int n = t >> 2, d0 = (t & 3) * 8;
        size_t base = (size_t)(w * 64 + n) * C3 + h * 32 + d0;
        bf16x8 vq = *(const bf16x8*)&qkv[base];
        bf16x8 vk = *(const bf16x8*)&qkv[base + 192];
        bf16x8 vv = *(const bf16x8*)&qkv[base + 384];
        #pragma unroll
        for (int i = 0; i < 8; i++) {
            qT[d0 + i][n]  = b2f((bfu)vq[i]);
            kT[d0 + i][n]  = b2f((bfu)vk[i]);
            vsm[n][d0 + i] = b2f((bfu)vv[i]);
        }
    }
    __syncthreads();

    {
        const int i0 = (t >> 4) * 4, j0 = (t & 15) * 4;
        float sacc[4][4] = {};
        #pragma unroll
        for (int kk = 0; kk < 32; kk++) {
            float4 q4 = *reinterpret_cast<float4*>(&qT[kk][i0]);
            float4 k4 = *reinterpret_cast<float4*>(&kT[kk][j0]);
            float qa[4] = {q4.x, q4.y, q4.z, q4.w};
            float kb[4] = {k4.x, k4.y, k4.z, k4.w};
            #pragma unroll
            for (int a = 0; a < 4; a++)
                #pragma unroll
                for (int b = 0; b < 4; b++)
                    sacc[a][b] += qa[a] * kb[b];
        }
        #pragma unroll
        for (int a = 0; a < 4; a++) {
            int i = i0 + a;
            #pragma unroll
            for (int b = 0; b < 4; b++) {
                int j = j0 + b;
                int rel = ((i >> 3) - (j >> 3) + 7) * 15 + ((i & 7) - (j & 7) + 7);
                S[i][j] = sacc[a][b] * 0.17677669529663687f + bias_s[rel * 6 + h];
            }
        }
    }
    __syncthreads();

    {
        const int r = t >> 2, q = (t & 3) * 16;
        float mx = -1e30f;
        #pragma unroll
        for (int j = 0; j < 16; j++) mx = fmaxf(mx, S[r][q + j]);
        mx = fmaxf(mx, __shfl_xor(mx, 1));
        mx = fmaxf(mx, __shfl_xor(mx, 2));
        float sm = 0.f;
        #pragma unroll
        for (int j = 0; j < 16; j++) { float e = __expf(S[r][q + j] - mx); S[r][q + j] = e; sm += e; }
        sm += __shfl_xor(sm, 1);
        sm += __shfl_xor(sm, 2);
        float inv = 1.0f / sm;
        #pragma unroll
        for (int j = 0; j < 16; j++) S[r][q + j] *= inv;
    }
    __syncthreads();

    {
        const int oi = (t >> 4) * 4, d0 = (t & 15) * 2;
        float a0 = 0, a1 = 0, a2 = 0, a3 = 0, c0 = 0, c1 = 0, c2 = 0, c3 = 0;
        for (int j = 0; j < 64; j++) {
            float2 vj = *reinterpret_cast<float2*>(&vsm[j][d0]);
            float s0 = S[oi][j], s1 = S[oi + 1][j], s2 = S[oi + 2][j], s3 = S[oi + 3][j];
            a0 += s0 * vj.x; c0 += s0 * vj.y;
            a1 += s1 * vj.x; c1 += s1 * vj.y;
            a2 += s2 * vj.x; c2 += s2 * vj.y;
            a3 += s3 * vj.x; c3 += s3 * vj.y;
        }
        float oa[4] = {a0, a1, a2, a3}, ob[4] = {c0, c1, c2, c3};
        #pragma unroll
        for (int a = 0; a < 4; a++) {
            size_t o = (size_t)(w * 64 + oi + a) * CC + h * 32 + d0;
            unsigned pk = (unsigned)f2b(oa[a]) | ((unsigned)f2b(ob[a]) << 16);
            *(unsigned*)&outp[o] = pk;
        }
    }
}

// ---------------- launch ----------------
extern "C" void kernel_launch(void* const* d_in, const int* in_sizes, int n_in,
                              void* d_out, int out_size, void* d_ws, size_t ws_size,
                              hipStream_t stream)
{
    const void* x      = d_in[0];
    const void* qkv_w  = d_in[1];
    const void* qkv_b  = d_in[2];
    const void* proj_w = d_in[3];
    const void* proj_b = d_in[4];
    const void* rpb    = d_in[5];
    const void* n1s    = d_in[6];
    const void* n1b    = d_in[7];
    const void* n2s    = d_in[8];
    const void* n2b    = d_in[9];
    const void* w1     = d_in[10];
    const void* b1     = d_in[11];
    const void* w2     = d_in[12];
    const void* b2     = d_in[13];

    // per-chunk intermediates: <=2048 B/row (phase1: xw 384 + qkvc 1152 + ao 384 B)
    int nch = 1;
    while (nch < 128 && ((size_t)(MROWS / nch) * 2048 + 1024 + WBYTES) > ws_size) nch *= 2;
    const int R = MROWS / nch;

    int* flag = (int*)d_ws;
    bfu* wb   = (bfu*)((char*)d_ws + 1024);
    // weight areas (bfu offsets; slots sized from the old padded layout, still fit)
    bfu* wqH = wb;           bfu* wqL = wb + 122880;   // 576x192 (uses 110592)
    bfu* wpH = wb + 245760;  bfu* wpL = wb + 294912;   // 192x192 (uses 36864)
    bfu* w1H = wb + 344064;  bfu* w1L = wb + 491520;   // 768x192 (uses 147456)
    bfu* w2H = wb + 638976;  bfu* w2L = wb + 835584;   // 192x768 (uses 147456)
    bfu* fB  = wb + 1032192;                           // chunk area

    // phase 1 layout (bfu units): xw R*192 | qkvc R*576 | ao R*192
    bfu* xw   = fB;
    bfu* qkvc = fB + (size_t)R * 192;
    bfu* ao   = fB + (size_t)R * 768;
    // phase 2 layout: xn R*192 | hb R*768
    bfu* xn   = fB;
    bfu* hb   = fB + (size_t)R * 192;

    detect_kernel<<<1, 256, 0, stream>>>(x, flag);
    prep_kernel<<<dim3(3, 576),  64, 0, stream>>>(flag, qkv_w,  wqH, wqL, 192, 576);
    prep_kernel<<<dim3(3, 192),  64, 0, stream>>>(flag, proj_w, wpH, wpL, 192, 192);
    prep_kernel<<<dim3(3, 768),  64, 0, stream>>>(flag, w1,     w1H, w1L, 192, 768);
    prep_kernel<<<dim3(12, 192), 64, 0, stream>>>(flag, w2,     w2H, w2L, 768, 192);

    // phase 1: LN1+shift+window -> qkv -> attn -> proj+unshift+residual(x) -> d_out
    for (int c = 0; c < nch; c++) {
        const int row0 = c * R;
        ln_kernel<true><<<R, 64, 0, stream>>>(flag, x, n1s, n1b, xw, row0);
        gemm_kernel<0><<<dim3(9, R / 128), 256, 0, stream>>>(
            flag, xw, wqH, wqL, qkv_b, nullptr, qkvc, 192, C3, 576, 0);
        attn_kernel<<<(R / 64) * 6, 256, 0, stream>>>(flag, qkvc, rpb, ao);
        gemm_kernel<1><<<dim3(3, R / 128), 256, 0, stream>>>(
            flag, ao, wpH, wpL, proj_b, x, d_out, 192, CC, CC, row0);
    }

    // phase 2: LN2 -> mlp1+gelu -> mlp2+residual ; x2 lives in d_out (global rows)
    for (int c = 0; c < nch; c++) {
        const int row0 = c * R;
        ln_kernel<false><<<R, 64, 0, stream>>>(flag, d_out, n2s, n2b, xn, row0);
        gemm_kernel<2><<<dim3(12, R / 128), 256, 0, stream>>>(
            flag, xn, w1H, w1L, b1, nullptr, hb, 192, CM, CM, 0);
        gemm_kernel<3><<<dim3(3, R / 128), 256, 0, stream>>>(
            flag, hb, w2H, w2L, b2, d_out, d_out, 768, CC, CC, row0);
    }
}